// Round 11
// baseline (265.699 us; speedup 1.0000x reference)
//
#include <hip/hip_runtime.h>
#include <hip/hip_bf16.h>

// Problem constants (reference: B=2, S=2048, D=1024, H=16, DEPTH=64)
constexpr int Bn = 2, Sn = 2048, Dn = 1024, Hn = 16, DEP = 64;
constexpr int NTOKn = Bn * Sn;  // 4096 rows for the token-dim GEMMs

typedef __bf16 bf16x8 __attribute__((ext_vector_type(8)));
typedef float f32x4 __attribute__((ext_vector_type(4)));

__device__ __forceinline__ unsigned short f2bf(float f) {
    union { __hip_bfloat16 h; unsigned short u; } cv;
    cv.h = __float2bfloat16(f);
    return cv.u;
}

// async global->LDS, 16B per lane. LDS dest must be wave-uniform base + lane*16.
__device__ __forceinline__ void gll16(const void* g, void* l) {
    __builtin_amdgcn_global_load_lds(
        (const __attribute__((address_space(1))) unsigned int*)g,
        (__attribute__((address_space(3))) unsigned int*)l, 16, 0, 0);
}

// ---------------- fused prep: x f32->bf16 convert + 4x weight transpose ----------------
__global__ __launch_bounds__(256) void k_prep(const float* __restrict__ x,
                                              const float* __restrict__ w0,
                                              const float* __restrict__ w1,
                                              const float* __restrict__ w2,
                                              const float* __restrict__ w3,
                                              unsigned short* __restrict__ xb,
                                              unsigned short* __restrict__ t0,
                                              unsigned short* __restrict__ t1,
                                              unsigned short* __restrict__ t2,
                                              unsigned short* __restrict__ t3) {
    const int bid = blockIdx.x;
    const int t = threadIdx.x;
    if (bid < 4096) {
        const int idx = (bid * 256 + t) * 4;
        float4 v = *reinterpret_cast<const float4*>(x + idx);
        ushort4 o;
        o.x = f2bf(v.x); o.y = f2bf(v.y); o.z = f2bf(v.z); o.w = f2bf(v.w);
        *reinterpret_cast<ushort4*>(xb + idx) = o;
        return;
    }
    const int b2 = bid - 4096;
    const float* w; unsigned short* tp;
    switch (b2 >> 8) {
        case 0: w = w0; tp = t0; break;
        case 1: w = w1; tp = t1; break;
        case 2: w = w2; tp = t2; break;
        default: w = w3; tp = t3; break;
    }
    __shared__ unsigned short tile[64][65];
    const int k0 = ((b2 & 255) >> 4) * 64, n0 = (b2 & 15) * 64;
    const int c = t & 63, rb = t >> 6;
#pragma unroll
    for (int i = 0; i < 16; ++i) {
        int r = rb + i * 4;
        tile[r][c] = f2bf(w[(size_t)(k0 + r) * Dn + n0 + c]);
    }
    __syncthreads();
#pragma unroll
    for (int i = 0; i < 16; ++i) {
        int n = rb + i * 4;
        tp[(size_t)(n0 + n) * Dn + k0 + c] = tile[c][n];
    }
}

// =================== QKV GEMM, 8-phase-style 256x256 tile ===================
// (counted vmcnt(4), T2 slot-swizzle, T5 setprio)
// Epilogue: Q/K blocks write qkv[z][token][dim]; V blocks (z==2) write the
// TRANSPOSED vT[(b*1024+col)][s] directly as ushort4.
__global__ __launch_bounds__(512, 2) void k_qkv8(const unsigned short* __restrict__ A,
                                                 const unsigned short* __restrict__ Bt,
                                                 const float* __restrict__ bq,
                                                 const float* __restrict__ bk,
                                                 const float* __restrict__ bv,
                                                 unsigned short* __restrict__ qkv,
                                                 unsigned short* __restrict__ vT) {
    extern __shared__ char smem[];  // 131072 bytes
    constexpr int K = 1024, NT = K / 64;  // 16 K-steps

    const int t = threadIdx.x;
    const int w = t >> 6, l = t & 63;
    const int wm = w >> 2, wn = w & 3;
    const int m0 = blockIdx.x * 256;
    const int n0 = blockIdx.y * 256;
    const int z = n0 >> 10;

    const float* bias = (z == 0) ? bq : (z == 1 ? bk : bv);
    float biasv[4];
#pragma unroll
    for (int nf = 0; nf < 4; ++nf)
        biasv[nf] = bias[(n0 + wn * 64 + nf * 16 + (l & 15)) & 1023];

    int aoff[2], boff[2], ldsoff[2];
#pragma unroll
    for (int i = 0; i < 2; ++i) {
        const int idx = i * 512 + t;
        const int row = idx >> 2;
        const int s = ((idx & 3) - row - (row >> 2)) & 3;
        aoff[i] = (m0 + row) * K + s * 8;
        boff[i] = (n0 + row) * K + s * 8;
        ldsoff[i] = idx * 16;
    }

    f32x4 acc[8][4] = {};

#pragma unroll
    for (int kh = 0; kh < 2; ++kh) {
        if (kh == 0) {
#pragma unroll
            for (int i = 0; i < 2; ++i) gll16(A + aoff[i], smem + ldsoff[i]);
#pragma unroll
            for (int i = 0; i < 2; ++i) gll16(Bt + boff[i], smem + 65536 + ldsoff[i]);
        } else {
#pragma unroll
            for (int i = 0; i < 2; ++i) gll16(A + aoff[i] + 32, smem + 16384 + ldsoff[i]);
#pragma unroll
            for (int i = 0; i < 2; ++i) gll16(Bt + boff[i] + 32, smem + 65536 + 16384 + ldsoff[i]);
        }
    }

    for (int kb = 0; kb < NT; ++kb) {
        const int c = kb & 1;
        const int kn = (kb + 1 < NT) ? kb + 1 : NT - 1;
        const int cn = c ^ 1;
        const int Abase = c * 32768;
        const int Bbase = 65536 + c * 32768;
        const int AbaseN = cn * 32768;
        const int BbaseN = 65536 + cn * 32768;

        bf16x8 bf[4], af[4];

#pragma unroll
        for (int ph = 0; ph < 4; ++ph) {
            const int kk = ph >> 1;
            const int mb = (ph & 1) * 4;

            if ((ph & 1) == 0) {
                asm volatile("s_waitcnt vmcnt(4)" ::: "memory");
            }
            __builtin_amdgcn_s_barrier();
            __builtin_amdgcn_sched_barrier(0);

            if ((ph & 1) == 0) {
#pragma unroll
                for (int nf = 0; nf < 4; ++nf) {
                    const int row = wn * 64 + nf * 16 + (l & 15);
                    const int byte = Bbase + kk * 16384 + row * 64 +
                                     ((((l >> 4) + row + (row >> 2)) & 3) * 16);
                    bf[nf] = *reinterpret_cast<const bf16x8*>(smem + byte);
                }
            }
#pragma unroll
            for (int mfl = 0; mfl < 4; ++mfl) {
                const int row = wm * 128 + (mb + mfl) * 16 + (l & 15);
                const int byte = Abase + kk * 16384 + row * 64 +
                                 ((((l >> 4) + row + (row >> 2)) & 3) * 16);
                af[mfl] = *reinterpret_cast<const bf16x8*>(smem + byte);
            }

            {
                const int khs = ph >> 1;
                if ((ph & 1) == 0) {
#pragma unroll
                    for (int i = 0; i < 2; ++i)
                        gll16(A + aoff[i] + kn * 64 + khs * 32,
                              smem + AbaseN + khs * 16384 + ldsoff[i]);
                } else {
#pragma unroll
                    for (int i = 0; i < 2; ++i)
                        gll16(Bt + boff[i] + kn * 64 + khs * 32,
                              smem + BbaseN + khs * 16384 + ldsoff[i]);
                }
            }

            asm volatile("s_waitcnt lgkmcnt(0)" ::: "memory");
            __builtin_amdgcn_sched_barrier(0);
            __builtin_amdgcn_s_setprio(1);
#pragma unroll
            for (int mfl = 0; mfl < 4; ++mfl)
#pragma unroll
                for (int nf = 0; nf < 4; ++nf)
                    acc[mb + mfl][nf] = __builtin_amdgcn_mfma_f32_16x16x32_bf16(
                        af[mfl], bf[nf], acc[mb + mfl][nf], 0, 0, 0);
            __builtin_amdgcn_s_setprio(0);
        }
    }

    asm volatile("s_waitcnt vmcnt(0)" ::: "memory");

    if (z < 2) {
        unsigned short* outz = qkv + (size_t)z * NTOKn * Dn;
#pragma unroll
        for (int mf = 0; mf < 8; ++mf) {
            const int row = m0 + wm * 128 + mf * 16 + (l >> 4) * 4;
#pragma unroll
            for (int nf = 0; nf < 4; ++nf) {
                const int col = (n0 + wn * 64 + nf * 16 + (l & 15)) & 1023;
#pragma unroll
                for (int i = 0; i < 4; ++i)
                    outz[(size_t)(row + i) * Dn + col] = f2bf(acc[mf][nf][i] + biasv[nf]);
            }
        }
    } else {
        // V: write transposed vT[(b*1024 + col)][s], 4 consecutive s per lane
#pragma unroll
        for (int mf = 0; mf < 8; ++mf) {
            const int row = m0 + wm * 128 + mf * 16 + (l >> 4) * 4;
            const int b = row >> 11, s = row & 2047;
#pragma unroll
            for (int nf = 0; nf < 4; ++nf) {
                const int col = (n0 + wn * 64 + nf * 16 + (l & 15)) & 1023;
                ushort4 o;
                o.x = f2bf(acc[mf][nf][0] + biasv[nf]);
                o.y = f2bf(acc[mf][nf][1] + biasv[nf]);
                o.z = f2bf(acc[mf][nf][2] + biasv[nf]);
                o.w = f2bf(acc[mf][nf][3] + biasv[nf]);
                *reinterpret_cast<ushort4*>(vT + ((size_t)(b * 1024 + col)) * Sn + s) = o;
            }
        }
    }
}

// ---------------- bf16 GEMM (m97 structure, 128x128) for the out-projection ----------------
__global__ __launch_bounds__(256) void k_gemm_op(const unsigned short* __restrict__ A,
                                                 const unsigned short* __restrict__ Bt,
                                                 const float* __restrict__ bias,
                                                 float* __restrict__ C,
                                                 int M, int N, int K) {
    __shared__ unsigned short As[128][32];
    __shared__ unsigned short Bs[128][32];
    const int t = threadIdx.x;
    const int w = t >> 6, l = t & 63;
    const int m0 = blockIdx.x * 128, n0 = blockIdx.y * 128;
    const int wr = (w >> 1) * 64, wc = (w & 1) * 64;

    const int lrow = t >> 2;
    const int lcol = (t & 3) * 8;
    const unsigned short* gA = A + (size_t)(m0 + lrow) * K + lcol;
    const unsigned short* gB = Bt + (size_t)(n0 + lrow) * K + lcol;
    unsigned short* lA = &As[0][0] + t * 8;
    unsigned short* lB = &Bs[0][0] + t * 8;

    f32x4 acc[4][4] = {};

    for (int k0 = 0; k0 < K; k0 += 32) {
        __syncthreads();
        gll16(gA + k0, lA);
        gll16(gA + (size_t)64 * K + k0, lA + 2048);
        gll16(gB + k0, lB);
        gll16(gB + (size_t)64 * K + k0, lB + 2048);
        __syncthreads();

        bf16x8 af[4], bfv[4];
#pragma unroll
        for (int i = 0; i < 4; ++i)
            af[i] = *reinterpret_cast<const bf16x8*>(&As[wr + i * 16 + (l & 15)][(l >> 4) * 8]);
#pragma unroll
        for (int i = 0; i < 4; ++i)
            bfv[i] = *reinterpret_cast<const bf16x8*>(&Bs[wc + i * 16 + (l & 15)][(l >> 4) * 8]);
#pragma unroll
        for (int mi = 0; mi < 4; ++mi)
#pragma unroll
            for (int ni = 0; ni < 4; ++ni)
                acc[mi][ni] =
                    __builtin_amdgcn_mfma_f32_16x16x32_bf16(af[mi], bfv[ni], acc[mi][ni], 0, 0, 0);
    }

#pragma unroll
    for (int mi = 0; mi < 4; ++mi) {
        const int row = m0 + wr + mi * 16 + (l >> 4) * 4;
#pragma unroll
        for (int ni = 0; ni < 4; ++ni) {
            const int col = n0 + wc + ni * 16 + (l & 15);
            const float bv = bias[col];
#pragma unroll
            for (int i = 0; i < 4; ++i)
                C[(size_t)(row + i) * N + col] = acc[mi][ni][i] + bv;
        }
    }
}

// ---------------- fused attention: attn = relu(QK^T*scale), ctx = attn @ V ----------------
// PRODUCER/CONSUMER: 6 waves = 4 compute + 2 store. Compute waves never issue
// global stores in the loop (their vmcnt(0) counts ONLY their 8 gll16 loads —
// no load/store entanglement). Store waves read bf16 Ps (written for PV) and
// stream f32 full-line stores with NO vmcnt waits (63-deep queue backpressure).
// 3 barriers/iter for all waves: B (tile resident), C (Ps ready), A (Ps/K/V
// reads certified before overwrite). Numerics identical to R10.
__global__ __launch_bounds__(384, 3) void k_attn(const unsigned short* __restrict__ Qb,
                                                 const unsigned short* __restrict__ Kb,
                                                 const unsigned short* __restrict__ VTb,
                                                 float* __restrict__ attn,
                                                 unsigned short* __restrict__ ctx) {
    __shared__ unsigned short Ks[128 * 64];
    __shared__ unsigned short Vs[64 * 128];
    __shared__ unsigned short Ps[4][32][136];
    constexpr int NT = Sn / 128;  // 16

    const int t = threadIdx.x;
    const int w = t >> 6, l = t & 63;  // w in 0..5

    // XCD-aware bijective remap (dispatch round-robins linear%8 across XCDs)
    const int lin = blockIdx.x + 16 * blockIdx.y;
    const int xcd = lin & 7, idx = lin >> 3;
    const int bh = xcd * 4 + (idx >> 4);
    const int q0 = (idx & 15) * 128;
    const int b = bh >> 4, h = bh & 15;
    const float scale = 0.125f;  // 1/sqrt(64)

    if (w < 4) {
        // ================= compute waves (t in 0..255) =================
        bf16x8 qf[2][2];
#pragma unroll
        for (int mi = 0; mi < 2; ++mi)
#pragma unroll
            for (int kk = 0; kk < 2; ++kk)
                qf[mi][kk] = *reinterpret_cast<const bf16x8*>(
                    Qb + (size_t)(b * Sn + q0 + w * 32 + mi * 16 + (l & 15)) * Dn + h * DEP +
                    kk * 32 + (l >> 4) * 8);

        const int krow = t >> 3;
        const int kcolswz = ((t & 7) * 8) ^ ((krow & 7) << 3);
        const int vrow = t >> 4;
        const int vcolswz = ((t & 15) * 8) ^ ((vrow & 7) << 3);
        unsigned short* lK = Ks + t * 8;
        unsigned short* lV = Vs + t * 8;

        f32x4 ctxa[2][4] = {};

        auto STAGE = [&](int kb) {
#pragma unroll
            for (int is = 0; is < 4; ++is) {
                gll16(Kb + (size_t)(b * Sn + kb * 128 + is * 32 + krow) * Dn + h * DEP + kcolswz,
                      lK + is * 2048);
                gll16(VTb + (size_t)(bh * DEP + is * 16 + vrow) * Sn + kb * 128 + vcolswz,
                      lV + is * 2048);
            }
        };

        auto QKT = [&]() {
            f32x4 sa[2][8];
#pragma unroll
            for (int mi = 0; mi < 2; ++mi)
#pragma unroll
                for (int nj = 0; nj < 8; ++nj)
                    sa[mi][nj] = (f32x4){0.f, 0.f, 0.f, 0.f};
#pragma unroll
            for (int nj = 0; nj < 8; ++nj) {
                const int kr = nj * 16 + (l & 15);
#pragma unroll
                for (int kk = 0; kk < 2; ++kk) {
                    const int kidx = (kr * 64 + kk * 32 + (l >> 4) * 8) ^ ((kr & 7) << 3);
                    const bf16x8 bfr = *reinterpret_cast<const bf16x8*>(Ks + kidx);
                    sa[0][nj] = __builtin_amdgcn_mfma_f32_16x16x32_bf16(qf[0][kk], bfr, sa[0][nj], 0, 0, 0);
                    sa[1][nj] = __builtin_amdgcn_mfma_f32_16x16x32_bf16(qf[1][kk], bfr, sa[1][nj], 0, 0, 0);
                }
            }
#pragma unroll
            for (int mi = 0; mi < 2; ++mi) {
#pragma unroll
                for (int nj = 0; nj < 8; ++nj) {
                    const int kc = nj * 16 + (l & 15);
#pragma unroll
                    for (int i = 0; i < 4; ++i) {
                        float p = sa[mi][nj][i] * scale;
                        p = p > 0.f ? p : 0.f;
                        Ps[w][mi * 16 + (l >> 4) * 4 + i][kc] = f2bf(p);
                    }
                }
            }
        };

        auto PV = [&]() {
            bf16x8 pf[2][4];
#pragma unroll
            for (int mi = 0; mi < 2; ++mi)
#pragma unroll
                for (int kk = 0; kk < 4; ++kk)
                    pf[mi][kk] = *reinterpret_cast<const bf16x8*>(
                        &Ps[w][mi * 16 + (l & 15)][kk * 32 + (l >> 4) * 8]);
#pragma unroll
            for (int nd = 0; nd < 4; ++nd) {
                const int vr = nd * 16 + (l & 15);
#pragma unroll
                for (int kk = 0; kk < 4; ++kk) {
                    const int vidx = (vr * 128 + kk * 32 + (l >> 4) * 8) ^ ((vr & 7) << 3);
                    const bf16x8 vfr = *reinterpret_cast<const bf16x8*>(Vs + vidx);
                    ctxa[0][nd] = __builtin_amdgcn_mfma_f32_16x16x32_bf16(pf[0][kk], vfr, ctxa[0][nd], 0, 0, 0);
                    ctxa[1][nd] = __builtin_amdgcn_mfma_f32_16x16x32_bf16(pf[1][kk], vfr, ctxa[1][nd], 0, 0, 0);
                }
            }
        };

        STAGE(0);
        for (int kb = 0; kb < NT; ++kb) {
            asm volatile("s_waitcnt vmcnt(0)" ::: "memory");   // my 8 loads only
            __builtin_amdgcn_s_barrier();                       // B: tile resident
            __builtin_amdgcn_sched_barrier(0);
            QKT();
            asm volatile("s_waitcnt lgkmcnt(0)" ::: "memory");  // Ps writes visible
            __builtin_amdgcn_s_barrier();                       // C: Ps ready
            __builtin_amdgcn_sched_barrier(0);
            PV();
            asm volatile("s_waitcnt lgkmcnt(0)" ::: "memory");  // my Ks/Vs/Ps reads done
            __builtin_amdgcn_s_barrier();                       // A: safe to overwrite
            if (kb < NT - 1) STAGE(kb + 1);
        }

        // ---- store ctx (bf16, head-concat layout [B*S][D]) ----
#pragma unroll
        for (int mi = 0; mi < 2; ++mi) {
#pragma unroll
            for (int nd = 0; nd < 4; ++nd) {
                const int dc = nd * 16 + (l & 15);
#pragma unroll
                for (int i = 0; i < 4; ++i) {
                    const int qr = q0 + w * 32 + mi * 16 + (l >> 4) * 4 + i;
                    ctx[(size_t)(b * Sn + qr) * Dn + h * DEP + dc] = f2bf(ctxa[mi][nd][i]);
                }
            }
        }
    } else {
        // ================= store waves (w = 4,5) =================
        const int sw = w - 4;  // handles q-rows [sw*64, sw*64+64)
        float* const abase = attn + (size_t)bh * Sn * Sn + (size_t)(q0 + sw * 64) * Sn;

        for (int kb = 0; kb < NT; ++kb) {
            __builtin_amdgcn_s_barrier();   // B
            __builtin_amdgcn_s_barrier();   // C: Ps[kb] ready
            float* arow = abase + kb * 128;
#pragma unroll
            for (int j = 0; j < 32; ++j) {
                const int row = (j & 7) * 8 + (l >> 3);       // 0..63 within half
                const int col = (l & 7) * 4 + (j >> 3) * 32;  // 0..127
                const int gr = sw * 64 + row;                 // 0..127 global
                ushort4 p = *reinterpret_cast<const ushort4*>(&Ps[gr >> 5][gr & 31][col]);
                f32x4 v;
                v[0] = __uint_as_float((unsigned)p.x << 16);
                v[1] = __uint_as_float((unsigned)p.y << 16);
                v[2] = __uint_as_float((unsigned)p.z << 16);
                v[3] = __uint_as_float((unsigned)p.w << 16);
                *reinterpret_cast<f32x4*>(arow + (size_t)row * Sn + col) = v;  // no vmcnt wait
            }
            asm volatile("s_waitcnt lgkmcnt(0)" ::: "memory");  // Ps reads retired
            __builtin_amdgcn_s_barrier();   // A: promise kept
        }
    }
}

extern "C" void kernel_launch(void* const* d_in, const int* in_sizes, int n_in,
                              void* d_out, int out_size, void* d_ws, size_t ws_size,
                              hipStream_t stream) {
    (void)in_sizes; (void)n_in; (void)out_size; (void)ws_size;
    const float* x  = (const float*)d_in[0];
    const float* wq = (const float*)d_in[1];
    const float* bq = (const float*)d_in[2];
    const float* wk = (const float*)d_in[3];
    const float* bk = (const float*)d_in[4];
    const float* wv = (const float*)d_in[5];
    const float* bv = (const float*)d_in[6];
    const float* wo = (const float*)d_in[7];
    const float* bo = (const float*)d_in[8];

    float* out  = (float*)d_out;
    float* attn = out + (size_t)Bn * Sn * Dn;  // outputs concatenated: (out, attn)

    char* ws = (char*)d_ws;
    unsigned short* xb = (unsigned short*)ws;  ws += (size_t)NTOKn * Dn * 2;       // 8 MB
    unsigned short* wT = (unsigned short*)ws;  ws += (size_t)4 * Dn * Dn * 2;      // 8 MB [q,k,v,o]
    unsigned short* qkv = (unsigned short*)ws; ws += (size_t)3 * NTOKn * Dn * 2;   // 24 MB (v third unused)
    unsigned short* vT = (unsigned short*)ws;  ws += (size_t)NTOKn * Dn * 2;       // 8 MB
    unsigned short* ctx = (unsigned short*)ws;                                     // 8 MB

    const size_t DD = (size_t)Dn * Dn;

    static bool attr_set = false;
    if (!attr_set) {
        hipFuncSetAttribute(reinterpret_cast<const void*>(k_qkv8),
                            hipFuncAttributeMaxDynamicSharedMemorySize, 131072);
        attr_set = true;
    }

    k_prep<<<dim3(5120), 256, 0, stream>>>(x, wq, wk, wv, wo, xb,
                                           wT, wT + DD, wT + 2 * DD, wT + 3 * DD);
    k_qkv8<<<dim3(16, 12), 512, 131072, stream>>>(xb, wT, bq, bk, bv, qkv, vT);
    k_attn<<<dim3(16, 32), 384, 0, stream>>>(qkv, qkv + (size_t)NTOKn * Dn, vT, attn, ctx);
    k_gemm_op<<<dim3(32, 8), 256, 0, stream>>>(ctx, wT + 3 * DD, bo, out, NTOKn, Dn, Dn);
}

// Round 12
// 262.358 us; speedup vs baseline: 1.0127x; 1.0127x over previous
//
#include <hip/hip_runtime.h>
#include <hip/hip_bf16.h>

// Problem constants (reference: B=2, S=2048, D=1024, H=16, DEPTH=64)
constexpr int Bn = 2, Sn = 2048, Dn = 1024, Hn = 16, DEP = 64;
constexpr int NTOKn = Bn * Sn;  // 4096 rows for the token-dim GEMMs

typedef __bf16 bf16x8 __attribute__((ext_vector_type(8)));
typedef float f32x4 __attribute__((ext_vector_type(4)));

__device__ __forceinline__ unsigned short f2bf(float f) {
    union { __hip_bfloat16 h; unsigned short u; } cv;
    cv.h = __float2bfloat16(f);
    return cv.u;
}

// async global->LDS, 16B per lane. LDS dest must be wave-uniform base + lane*16.
__device__ __forceinline__ void gll16(const void* g, void* l) {
    __builtin_amdgcn_global_load_lds(
        (const __attribute__((address_space(1))) unsigned int*)g,
        (__attribute__((address_space(3))) unsigned int*)l, 16, 0, 0);
}

// ---------------- fused prep: x f32->bf16 convert + 4x weight transpose ----------------
__global__ __launch_bounds__(256) void k_prep(const float* __restrict__ x,
                                              const float* __restrict__ w0,
                                              const float* __restrict__ w1,
                                              const float* __restrict__ w2,
                                              const float* __restrict__ w3,
                                              unsigned short* __restrict__ xb,
                                              unsigned short* __restrict__ t0,
                                              unsigned short* __restrict__ t1,
                                              unsigned short* __restrict__ t2,
                                              unsigned short* __restrict__ t3) {
    const int bid = blockIdx.x;
    const int t = threadIdx.x;
    if (bid < 4096) {
        const int idx = (bid * 256 + t) * 4;
        float4 v = *reinterpret_cast<const float4*>(x + idx);
        ushort4 o;
        o.x = f2bf(v.x); o.y = f2bf(v.y); o.z = f2bf(v.z); o.w = f2bf(v.w);
        *reinterpret_cast<ushort4*>(xb + idx) = o;
        return;
    }
    const int b2 = bid - 4096;
    const float* w; unsigned short* tp;
    switch (b2 >> 8) {
        case 0: w = w0; tp = t0; break;
        case 1: w = w1; tp = t1; break;
        case 2: w = w2; tp = t2; break;
        default: w = w3; tp = t3; break;
    }
    __shared__ unsigned short tile[64][65];
    const int k0 = ((b2 & 255) >> 4) * 64, n0 = (b2 & 15) * 64;
    const int c = t & 63, rb = t >> 6;
#pragma unroll
    for (int i = 0; i < 16; ++i) {
        int r = rb + i * 4;
        tile[r][c] = f2bf(w[(size_t)(k0 + r) * Dn + n0 + c]);
    }
    __syncthreads();
#pragma unroll
    for (int i = 0; i < 16; ++i) {
        int n = rb + i * 4;
        tp[(size_t)(n0 + n) * Dn + k0 + c] = tile[c][n];
    }
}

// =================== QKV GEMM, 8-phase-style 256x256 tile ===================
// (counted vmcnt(4), T2 slot-swizzle, T5 setprio)
// Epilogue: Q/K blocks write qkv[z][token][dim]; V blocks (z==2) write the
// TRANSPOSED vT[(b*1024+col)][s] directly as ushort4.
__global__ __launch_bounds__(512, 2) void k_qkv8(const unsigned short* __restrict__ A,
                                                 const unsigned short* __restrict__ Bt,
                                                 const float* __restrict__ bq,
                                                 const float* __restrict__ bk,
                                                 const float* __restrict__ bv,
                                                 unsigned short* __restrict__ qkv,
                                                 unsigned short* __restrict__ vT) {
    extern __shared__ char smem[];  // 131072 bytes
    constexpr int K = 1024, NT = K / 64;  // 16 K-steps

    const int t = threadIdx.x;
    const int w = t >> 6, l = t & 63;
    const int wm = w >> 2, wn = w & 3;
    const int m0 = blockIdx.x * 256;
    const int n0 = blockIdx.y * 256;
    const int z = n0 >> 10;

    const float* bias = (z == 0) ? bq : (z == 1 ? bk : bv);
    float biasv[4];
#pragma unroll
    for (int nf = 0; nf < 4; ++nf)
        biasv[nf] = bias[(n0 + wn * 64 + nf * 16 + (l & 15)) & 1023];

    int aoff[2], boff[2], ldsoff[2];
#pragma unroll
    for (int i = 0; i < 2; ++i) {
        const int idx = i * 512 + t;
        const int row = idx >> 2;
        const int s = ((idx & 3) - row - (row >> 2)) & 3;
        aoff[i] = (m0 + row) * K + s * 8;
        boff[i] = (n0 + row) * K + s * 8;
        ldsoff[i] = idx * 16;
    }

    f32x4 acc[8][4] = {};

#pragma unroll
    for (int kh = 0; kh < 2; ++kh) {
        if (kh == 0) {
#pragma unroll
            for (int i = 0; i < 2; ++i) gll16(A + aoff[i], smem + ldsoff[i]);
#pragma unroll
            for (int i = 0; i < 2; ++i) gll16(Bt + boff[i], smem + 65536 + ldsoff[i]);
        } else {
#pragma unroll
            for (int i = 0; i < 2; ++i) gll16(A + aoff[i] + 32, smem + 16384 + ldsoff[i]);
#pragma unroll
            for (int i = 0; i < 2; ++i) gll16(Bt + boff[i] + 32, smem + 65536 + 16384 + ldsoff[i]);
        }
    }

    for (int kb = 0; kb < NT; ++kb) {
        const int c = kb & 1;
        const int kn = (kb + 1 < NT) ? kb + 1 : NT - 1;
        const int cn = c ^ 1;
        const int Abase = c * 32768;
        const int Bbase = 65536 + c * 32768;
        const int AbaseN = cn * 32768;
        const int BbaseN = 65536 + cn * 32768;

        bf16x8 bf[4], af[4];

#pragma unroll
        for (int ph = 0; ph < 4; ++ph) {
            const int kk = ph >> 1;
            const int mb = (ph & 1) * 4;

            if ((ph & 1) == 0) {
                asm volatile("s_waitcnt vmcnt(4)" ::: "memory");
            }
            __builtin_amdgcn_s_barrier();
            __builtin_amdgcn_sched_barrier(0);

            if ((ph & 1) == 0) {
#pragma unroll
                for (int nf = 0; nf < 4; ++nf) {
                    const int row = wn * 64 + nf * 16 + (l & 15);
                    const int byte = Bbase + kk * 16384 + row * 64 +
                                     ((((l >> 4) + row + (row >> 2)) & 3) * 16);
                    bf[nf] = *reinterpret_cast<const bf16x8*>(smem + byte);
                }
            }
#pragma unroll
            for (int mfl = 0; mfl < 4; ++mfl) {
                const int row = wm * 128 + (mb + mfl) * 16 + (l & 15);
                const int byte = Abase + kk * 16384 + row * 64 +
                                 ((((l >> 4) + row + (row >> 2)) & 3) * 16);
                af[mfl] = *reinterpret_cast<const bf16x8*>(smem + byte);
            }

            {
                const int khs = ph >> 1;
                if ((ph & 1) == 0) {
#pragma unroll
                    for (int i = 0; i < 2; ++i)
                        gll16(A + aoff[i] + kn * 64 + khs * 32,
                              smem + AbaseN + khs * 16384 + ldsoff[i]);
                } else {
#pragma unroll
                    for (int i = 0; i < 2; ++i)
                        gll16(Bt + boff[i] + kn * 64 + khs * 32,
                              smem + BbaseN + khs * 16384 + ldsoff[i]);
                }
            }

            asm volatile("s_waitcnt lgkmcnt(0)" ::: "memory");
            __builtin_amdgcn_sched_barrier(0);
            __builtin_amdgcn_s_setprio(1);
#pragma unroll
            for (int mfl = 0; mfl < 4; ++mfl)
#pragma unroll
                for (int nf = 0; nf < 4; ++nf)
                    acc[mb + mfl][nf] = __builtin_amdgcn_mfma_f32_16x16x32_bf16(
                        af[mfl], bf[nf], acc[mb + mfl][nf], 0, 0, 0);
            __builtin_amdgcn_s_setprio(0);
        }
    }

    asm volatile("s_waitcnt vmcnt(0)" ::: "memory");

    if (z < 2) {
        unsigned short* outz = qkv + (size_t)z * NTOKn * Dn;
#pragma unroll
        for (int mf = 0; mf < 8; ++mf) {
            const int row = m0 + wm * 128 + mf * 16 + (l >> 4) * 4;
#pragma unroll
            for (int nf = 0; nf < 4; ++nf) {
                const int col = (n0 + wn * 64 + nf * 16 + (l & 15)) & 1023;
#pragma unroll
                for (int i = 0; i < 4; ++i)
                    outz[(size_t)(row + i) * Dn + col] = f2bf(acc[mf][nf][i] + biasv[nf]);
            }
        }
    } else {
        // V: write transposed vT[(b*1024 + col)][s], 4 consecutive s per lane
#pragma unroll
        for (int mf = 0; mf < 8; ++mf) {
            const int row = m0 + wm * 128 + mf * 16 + (l >> 4) * 4;
            const int b = row >> 11, s = row & 2047;
#pragma unroll
            for (int nf = 0; nf < 4; ++nf) {
                const int col = (n0 + wn * 64 + nf * 16 + (l & 15)) & 1023;
                ushort4 o;
                o.x = f2bf(acc[mf][nf][0] + biasv[nf]);
                o.y = f2bf(acc[mf][nf][1] + biasv[nf]);
                o.z = f2bf(acc[mf][nf][2] + biasv[nf]);
                o.w = f2bf(acc[mf][nf][3] + biasv[nf]);
                *reinterpret_cast<ushort4*>(vT + ((size_t)(b * 1024 + col)) * Sn + s) = o;
            }
        }
    }
}

// ---------------- bf16 GEMM (m97 structure, 128x128) for the out-projection ----------------
__global__ __launch_bounds__(256) void k_gemm_op(const unsigned short* __restrict__ A,
                                                 const unsigned short* __restrict__ Bt,
                                                 const float* __restrict__ bias,
                                                 float* __restrict__ C,
                                                 int M, int N, int K) {
    __shared__ unsigned short As[128][32];
    __shared__ unsigned short Bs[128][32];
    const int t = threadIdx.x;
    const int w = t >> 6, l = t & 63;
    const int m0 = blockIdx.x * 128, n0 = blockIdx.y * 128;
    const int wr = (w >> 1) * 64, wc = (w & 1) * 64;

    const int lrow = t >> 2;
    const int lcol = (t & 3) * 8;
    const unsigned short* gA = A + (size_t)(m0 + lrow) * K + lcol;
    const unsigned short* gB = Bt + (size_t)(n0 + lrow) * K + lcol;
    unsigned short* lA = &As[0][0] + t * 8;
    unsigned short* lB = &Bs[0][0] + t * 8;

    f32x4 acc[4][4] = {};

    for (int k0 = 0; k0 < K; k0 += 32) {
        __syncthreads();
        gll16(gA + k0, lA);
        gll16(gA + (size_t)64 * K + k0, lA + 2048);
        gll16(gB + k0, lB);
        gll16(gB + (size_t)64 * K + k0, lB + 2048);
        __syncthreads();

        bf16x8 af[4], bfv[4];
#pragma unroll
        for (int i = 0; i < 4; ++i)
            af[i] = *reinterpret_cast<const bf16x8*>(&As[wr + i * 16 + (l & 15)][(l >> 4) * 8]);
#pragma unroll
        for (int i = 0; i < 4; ++i)
            bfv[i] = *reinterpret_cast<const bf16x8*>(&Bs[wc + i * 16 + (l & 15)][(l >> 4) * 8]);
#pragma unroll
        for (int mi = 0; mi < 4; ++mi)
#pragma unroll
            for (int ni = 0; ni < 4; ++ni)
                acc[mi][ni] =
                    __builtin_amdgcn_mfma_f32_16x16x32_bf16(af[mi], bfv[ni], acc[mi][ni], 0, 0, 0);
    }

#pragma unroll
    for (int mi = 0; mi < 4; ++mi) {
        const int row = m0 + wr + mi * 16 + (l >> 4) * 4;
#pragma unroll
        for (int ni = 0; ni < 4; ++ni) {
            const int col = n0 + wc + ni * 16 + (l & 15);
            const float bv = bias[col];
#pragma unroll
            for (int i = 0; i < 4; ++i)
                C[(size_t)(row + i) * N + col] = acc[mi][ni][i] + bv;
        }
    }
}

// ---------------- fused attention: attn = relu(QK^T*scale), ctx = attn @ V ----------------
// DECOUPLED STORES, 2 barriers/iter. 6 waves = 4 compute + 2 store. KVBLK=64
// (32 iters). K/V LDS double-buffered (STAGE right after barrier B hides load
// latency a full iter); Ps double-buffered (store waves stream tile k-1 from
// Ps[(k-1)&1] while compute writes Ps[k&1]). Compute waves issue NO global
// stores in-loop -> their vmcnt(0) counts only their own 4 loads (in-order
// retirement no longer chains loads behind the store backlog). Store waves
// have NO vmcnt waits ever (queue-cap backpressure = HBM drain rate).
// Numerics identical to R10 (bf16 Ps source).
__global__ __launch_bounds__(384, 3) void k_attn(const unsigned short* __restrict__ Qb,
                                                 const unsigned short* __restrict__ Kb,
                                                 const unsigned short* __restrict__ VTb,
                                                 float* __restrict__ attn,
                                                 unsigned short* __restrict__ ctx) {
    __shared__ unsigned short Ks[2][64 * 64];      // [buf][kv][d] 8KB each
    __shared__ unsigned short Vs[2][64 * 64];      // [buf][d][kv] 8KB each
    __shared__ unsigned short Ps[2][4][32][72];    // [buf][wave][qrow][kv+pad]
    constexpr int NT = Sn / 64;  // 32 kv-tiles

    const int t = threadIdx.x;
    const int w = t >> 6, l = t & 63;  // w in 0..5

    // XCD-aware bijective remap (dispatch round-robins linear%8 across XCDs)
    const int lin = blockIdx.x + 16 * blockIdx.y;
    const int xcd = lin & 7, idx = lin >> 3;
    const int bh = xcd * 4 + (idx >> 4);
    const int q0 = (idx & 15) * 128;
    const int b = bh >> 4, h = bh & 15;
    const float scale = 0.125f;  // 1/sqrt(64)

    if (w < 4) {
        // ================= compute waves (t in 0..255) =================
        bf16x8 qf[2][2];
#pragma unroll
        for (int mi = 0; mi < 2; ++mi)
#pragma unroll
            for (int kk = 0; kk < 2; ++kk)
                qf[mi][kk] = *reinterpret_cast<const bf16x8*>(
                    Qb + (size_t)(b * Sn + q0 + w * 32 + mi * 16 + (l & 15)) * Dn + h * DEP +
                    kk * 32 + (l >> 4) * 8);

        // staging: 64 rows x 128B per tile; 2 issues of 32 rows each
        const int srow = t >> 3;                                // 0..31
        const int scolswz = ((t & 7) * 8) ^ ((srow & 7) << 3);  // ushort col in [0,64)

        f32x4 ctxa[2][4] = {};

        auto STAGE = [&](int kb, int buf) {
            unsigned short* lK = Ks[buf] + t * 8;
            unsigned short* lV = Vs[buf] + t * 8;
#pragma unroll
            for (int is = 0; is < 2; ++is) {
                gll16(Kb + (size_t)(b * Sn + kb * 64 + is * 32 + srow) * Dn + h * DEP + scolswz,
                      lK + is * 2048);
                gll16(VTb + (size_t)(bh * DEP + is * 32 + srow) * Sn + kb * 64 + scolswz,
                      lV + is * 2048);
            }
        };

        auto QKT = [&](int buf) {
            f32x4 sa[2][4];
#pragma unroll
            for (int mi = 0; mi < 2; ++mi)
#pragma unroll
                for (int nj = 0; nj < 4; ++nj)
                    sa[mi][nj] = (f32x4){0.f, 0.f, 0.f, 0.f};
#pragma unroll
            for (int nj = 0; nj < 4; ++nj) {
                const int kr = nj * 16 + (l & 15);
#pragma unroll
                for (int kk = 0; kk < 2; ++kk) {
                    const int kidx = (kr * 64 + kk * 32 + (l >> 4) * 8) ^ ((kr & 7) << 3);
                    const bf16x8 bfr = *reinterpret_cast<const bf16x8*>(Ks[buf] + kidx);
                    sa[0][nj] = __builtin_amdgcn_mfma_f32_16x16x32_bf16(qf[0][kk], bfr, sa[0][nj], 0, 0, 0);
                    sa[1][nj] = __builtin_amdgcn_mfma_f32_16x16x32_bf16(qf[1][kk], bfr, sa[1][nj], 0, 0, 0);
                }
            }
#pragma unroll
            for (int mi = 0; mi < 2; ++mi) {
#pragma unroll
                for (int nj = 0; nj < 4; ++nj) {
                    const int kc = nj * 16 + (l & 15);
#pragma unroll
                    for (int i = 0; i < 4; ++i) {
                        float p = sa[mi][nj][i] * scale;
                        p = p > 0.f ? p : 0.f;
                        Ps[buf][w][mi * 16 + (l >> 4) * 4 + i][kc] = f2bf(p);
                    }
                }
            }
        };

        auto PV = [&](int buf) {
            bf16x8 pf[2][2];
#pragma unroll
            for (int mi = 0; mi < 2; ++mi)
#pragma unroll
                for (int kk = 0; kk < 2; ++kk)
                    pf[mi][kk] = *reinterpret_cast<const bf16x8*>(
                        &Ps[buf][w][mi * 16 + (l & 15)][kk * 32 + (l >> 4) * 8]);
#pragma unroll
            for (int nd = 0; nd < 4; ++nd) {
                const int vr = nd * 16 + (l & 15);
#pragma unroll
                for (int kk = 0; kk < 2; ++kk) {
                    const int vidx = (vr * 64 + kk * 32 + (l >> 4) * 8) ^ ((vr & 7) << 3);
                    const bf16x8 vfr = *reinterpret_cast<const bf16x8*>(Vs[buf] + vidx);
                    ctxa[0][nd] = __builtin_amdgcn_mfma_f32_16x16x32_bf16(pf[0][kk], vfr, ctxa[0][nd], 0, 0, 0);
                    ctxa[1][nd] = __builtin_amdgcn_mfma_f32_16x16x32_bf16(pf[1][kk], vfr, ctxa[1][nd], 0, 0, 0);
                }
            }
        };

        STAGE(0, 0);
        for (int kb = 0; kb < NT; ++kb) {
            const int buf = kb & 1;
            asm volatile("s_waitcnt vmcnt(0)" ::: "memory");    // my 4 loads only
            __builtin_amdgcn_s_barrier();                        // B: tile kb resident
            __builtin_amdgcn_sched_barrier(0);
            if (kb < NT - 1) STAGE(kb + 1, buf ^ 1);             // prefetch (other buffer)
            QKT(buf);
            PV(buf);
            asm volatile("s_waitcnt lgkmcnt(0)" ::: "memory");   // my LDS reads/writes done
            __builtin_amdgcn_s_barrier();                        // A: Ps[buf] handoff
        }

        // ---- store ctx (bf16, head-concat layout [B*S][D]) ----
#pragma unroll
        for (int mi = 0; mi < 2; ++mi) {
#pragma unroll
            for (int nd = 0; nd < 4; ++nd) {
                const int dc = nd * 16 + (l & 15);
#pragma unroll
                for (int i = 0; i < 4; ++i) {
                    const int qr = q0 + w * 32 + mi * 16 + (l >> 4) * 4 + i;
                    ctx[(size_t)(b * Sn + qr) * Dn + h * DEP + dc] = f2bf(ctxa[mi][nd][i]);
                }
            }
        }
    } else {
        // ================= store waves (w = 4,5) =================
        const int sw = w - 4;  // q-rows [sw*64, sw*64+64)
        float* const abase = attn + (size_t)bh * Sn * Sn + (size_t)(q0 + sw * 64) * Sn;

        auto STORE_TILE = [&](int kb) {  // stream tile kb from Ps[kb&1], no vmcnt waits
            float* arow = abase + kb * 64;
            const int buf = kb & 1;
#pragma unroll
            for (int j = 0; j < 16; ++j) {
                const int row = j * 4 + (l >> 4);      // 0..63 within my half
                const int gr = sw * 64 + row;          // 0..127 global q-row
                const int col = (l & 15) * 4;          // f32/kv col in [0,64)
                ushort4 p = *reinterpret_cast<const ushort4*>(&Ps[buf][gr >> 5][gr & 31][col]);
                f32x4 v;
                v[0] = __uint_as_float((unsigned)p.x << 16);
                v[1] = __uint_as_float((unsigned)p.y << 16);
                v[2] = __uint_as_float((unsigned)p.z << 16);
                v[3] = __uint_as_float((unsigned)p.w << 16);
                *reinterpret_cast<f32x4*>(arow + (size_t)row * Sn + col) = v;
            }
        };

        for (int kb = 0; kb < NT; ++kb) {
            __builtin_amdgcn_s_barrier();                        // B
            if (kb > 0) STORE_TILE(kb - 1);                      // Ps[(kb-1)&1] stable now
            asm volatile("s_waitcnt lgkmcnt(0)" ::: "memory");   // my Ps reads retired
            __builtin_amdgcn_s_barrier();                        // A
        }
        STORE_TILE(NT - 1);  // final tile (Ps stable after last A)
    }
}

extern "C" void kernel_launch(void* const* d_in, const int* in_sizes, int n_in,
                              void* d_out, int out_size, void* d_ws, size_t ws_size,
                              hipStream_t stream) {
    (void)in_sizes; (void)n_in; (void)out_size; (void)ws_size;
    const float* x  = (const float*)d_in[0];
    const float* wq = (const float*)d_in[1];
    const float* bq = (const float*)d_in[2];
    const float* wk = (const float*)d_in[3];
    const float* bk = (const float*)d_in[4];
    const float* wv = (const float*)d_in[5];
    const float* bv = (const float*)d_in[6];
    const float* wo = (const float*)d_in[7];
    const float* bo = (const float*)d_in[8];

    float* out  = (float*)d_out;
    float* attn = out + (size_t)Bn * Sn * Dn;  // outputs concatenated: (out, attn)

    char* ws = (char*)d_ws;
    unsigned short* xb = (unsigned short*)ws;  ws += (size_t)NTOKn * Dn * 2;       // 8 MB
    unsigned short* wT = (unsigned short*)ws;  ws += (size_t)4 * Dn * Dn * 2;      // 8 MB [q,k,v,o]
    unsigned short* qkv = (unsigned short*)ws; ws += (size_t)3 * NTOKn * Dn * 2;   // 24 MB (v third unused)
    unsigned short* vT = (unsigned short*)ws;  ws += (size_t)NTOKn * Dn * 2;       // 8 MB
    unsigned short* ctx = (unsigned short*)ws;                                     // 8 MB

    const size_t DD = (size_t)Dn * Dn;

    static bool attr_set = false;
    if (!attr_set) {
        hipFuncSetAttribute(reinterpret_cast<const void*>(k_qkv8),
                            hipFuncAttributeMaxDynamicSharedMemorySize, 131072);
        attr_set = true;
    }

    k_prep<<<dim3(5120), 256, 0, stream>>>(x, wq, wk, wv, wo, xb,
                                           wT, wT + DD, wT + 2 * DD, wT + 3 * DD);
    k_qkv8<<<dim3(16, 12), 512, 131072, stream>>>(xb, wT, bq, bk, bv, qkv, vT);
    k_attn<<<dim3(16, 32), 384, 0, stream>>>(qkv, qkv + (size_t)NTOKn * Dn, vT, attn, ctx);
    k_gemm_op<<<dim3(32, 8), 256, 0, stream>>>(ctx, wT + 3 * DD, bo, out, NTOKn, Dn, Dn);
}

// Round 13
// 214.252 us; speedup vs baseline: 1.2401x; 1.2245x over previous
//
#include <hip/hip_runtime.h>
#include <hip/hip_bf16.h>

// Problem constants (reference: B=2, S=2048, D=1024, H=16, DEPTH=64)
constexpr int Bn = 2, Sn = 2048, Dn = 1024, Hn = 16, DEP = 64;
constexpr int NTOKn = Bn * Sn;  // 4096 rows for the token-dim GEMMs

typedef __bf16 bf16x8 __attribute__((ext_vector_type(8)));
typedef float f32x4 __attribute__((ext_vector_type(4)));

__device__ __forceinline__ unsigned short f2bf(float f) {
    union { __hip_bfloat16 h; unsigned short u; } cv;
    cv.h = __float2bfloat16(f);
    return cv.u;
}

// async global->LDS, 16B per lane. LDS dest must be wave-uniform base + lane*16.
__device__ __forceinline__ void gll16(const void* g, void* l) {
    __builtin_amdgcn_global_load_lds(
        (const __attribute__((address_space(1))) unsigned int*)g,
        (__attribute__((address_space(3))) unsigned int*)l, 16, 0, 0);
}

// ---------------- fused prep: x f32->bf16 convert + 4x weight transpose ----------------
__global__ __launch_bounds__(256) void k_prep(const float* __restrict__ x,
                                              const float* __restrict__ w0,
                                              const float* __restrict__ w1,
                                              const float* __restrict__ w2,
                                              const float* __restrict__ w3,
                                              unsigned short* __restrict__ xb,
                                              unsigned short* __restrict__ t0,
                                              unsigned short* __restrict__ t1,
                                              unsigned short* __restrict__ t2,
                                              unsigned short* __restrict__ t3) {
    const int bid = blockIdx.x;
    const int t = threadIdx.x;
    if (bid < 4096) {
        const int idx = (bid * 256 + t) * 4;
        float4 v = *reinterpret_cast<const float4*>(x + idx);
        ushort4 o;
        o.x = f2bf(v.x); o.y = f2bf(v.y); o.z = f2bf(v.z); o.w = f2bf(v.w);
        *reinterpret_cast<ushort4*>(xb + idx) = o;
        return;
    }
    const int b2 = bid - 4096;
    const float* w; unsigned short* tp;
    switch (b2 >> 8) {
        case 0: w = w0; tp = t0; break;
        case 1: w = w1; tp = t1; break;
        case 2: w = w2; tp = t2; break;
        default: w = w3; tp = t3; break;
    }
    __shared__ unsigned short tile[64][65];
    const int k0 = ((b2 & 255) >> 4) * 64, n0 = (b2 & 15) * 64;
    const int c = t & 63, rb = t >> 6;
#pragma unroll
    for (int i = 0; i < 16; ++i) {
        int r = rb + i * 4;
        tile[r][c] = f2bf(w[(size_t)(k0 + r) * Dn + n0 + c]);
    }
    __syncthreads();
#pragma unroll
    for (int i = 0; i < 16; ++i) {
        int n = rb + i * 4;
        tp[(size_t)(n0 + n) * Dn + k0 + c] = tile[c][n];
    }
}

// =================== QKV GEMM, 8-phase-style 256x256 tile ===================
// (counted vmcnt(4), T2 slot-swizzle, T5 setprio)
// Epilogue: Q/K blocks write qkv[z][token][dim]; V blocks (z==2) write the
// TRANSPOSED vT[(b*1024+col)][s] directly as ushort4.
__global__ __launch_bounds__(512, 2) void k_qkv8(const unsigned short* __restrict__ A,
                                                 const unsigned short* __restrict__ Bt,
                                                 const float* __restrict__ bq,
                                                 const float* __restrict__ bk,
                                                 const float* __restrict__ bv,
                                                 unsigned short* __restrict__ qkv,
                                                 unsigned short* __restrict__ vT) {
    extern __shared__ char smem[];  // 131072 bytes
    constexpr int K = 1024, NT = K / 64;  // 16 K-steps

    const int t = threadIdx.x;
    const int w = t >> 6, l = t & 63;
    const int wm = w >> 2, wn = w & 3;
    const int m0 = blockIdx.x * 256;
    const int n0 = blockIdx.y * 256;
    const int z = n0 >> 10;

    const float* bias = (z == 0) ? bq : (z == 1 ? bk : bv);
    float biasv[4];
#pragma unroll
    for (int nf = 0; nf < 4; ++nf)
        biasv[nf] = bias[(n0 + wn * 64 + nf * 16 + (l & 15)) & 1023];

    int aoff[2], boff[2], ldsoff[2];
#pragma unroll
    for (int i = 0; i < 2; ++i) {
        const int idx = i * 512 + t;
        const int row = idx >> 2;
        const int s = ((idx & 3) - row - (row >> 2)) & 3;
        aoff[i] = (m0 + row) * K + s * 8;
        boff[i] = (n0 + row) * K + s * 8;
        ldsoff[i] = idx * 16;
    }

    f32x4 acc[8][4] = {};

#pragma unroll
    for (int kh = 0; kh < 2; ++kh) {
        if (kh == 0) {
#pragma unroll
            for (int i = 0; i < 2; ++i) gll16(A + aoff[i], smem + ldsoff[i]);
#pragma unroll
            for (int i = 0; i < 2; ++i) gll16(Bt + boff[i], smem + 65536 + ldsoff[i]);
        } else {
#pragma unroll
            for (int i = 0; i < 2; ++i) gll16(A + aoff[i] + 32, smem + 16384 + ldsoff[i]);
#pragma unroll
            for (int i = 0; i < 2; ++i) gll16(Bt + boff[i] + 32, smem + 65536 + 16384 + ldsoff[i]);
        }
    }

    for (int kb = 0; kb < NT; ++kb) {
        const int c = kb & 1;
        const int kn = (kb + 1 < NT) ? kb + 1 : NT - 1;
        const int cn = c ^ 1;
        const int Abase = c * 32768;
        const int Bbase = 65536 + c * 32768;
        const int AbaseN = cn * 32768;
        const int BbaseN = 65536 + cn * 32768;

        bf16x8 bf[4], af[4];

#pragma unroll
        for (int ph = 0; ph < 4; ++ph) {
            const int kk = ph >> 1;
            const int mb = (ph & 1) * 4;

            if ((ph & 1) == 0) {
                asm volatile("s_waitcnt vmcnt(4)" ::: "memory");
            }
            __builtin_amdgcn_s_barrier();
            __builtin_amdgcn_sched_barrier(0);

            if ((ph & 1) == 0) {
#pragma unroll
                for (int nf = 0; nf < 4; ++nf) {
                    const int row = wn * 64 + nf * 16 + (l & 15);
                    const int byte = Bbase + kk * 16384 + row * 64 +
                                     ((((l >> 4) + row + (row >> 2)) & 3) * 16);
                    bf[nf] = *reinterpret_cast<const bf16x8*>(smem + byte);
                }
            }
#pragma unroll
            for (int mfl = 0; mfl < 4; ++mfl) {
                const int row = wm * 128 + (mb + mfl) * 16 + (l & 15);
                const int byte = Abase + kk * 16384 + row * 64 +
                                 ((((l >> 4) + row + (row >> 2)) & 3) * 16);
                af[mfl] = *reinterpret_cast<const bf16x8*>(smem + byte);
            }

            {
                const int khs = ph >> 1;
                if ((ph & 1) == 0) {
#pragma unroll
                    for (int i = 0; i < 2; ++i)
                        gll16(A + aoff[i] + kn * 64 + khs * 32,
                              smem + AbaseN + khs * 16384 + ldsoff[i]);
                } else {
#pragma unroll
                    for (int i = 0; i < 2; ++i)
                        gll16(Bt + boff[i] + kn * 64 + khs * 32,
                              smem + BbaseN + khs * 16384 + ldsoff[i]);
                }
            }

            asm volatile("s_waitcnt lgkmcnt(0)" ::: "memory");
            __builtin_amdgcn_sched_barrier(0);
            __builtin_amdgcn_s_setprio(1);
#pragma unroll
            for (int mfl = 0; mfl < 4; ++mfl)
#pragma unroll
                for (int nf = 0; nf < 4; ++nf)
                    acc[mb + mfl][nf] = __builtin_amdgcn_mfma_f32_16x16x32_bf16(
                        af[mfl], bf[nf], acc[mb + mfl][nf], 0, 0, 0);
            __builtin_amdgcn_s_setprio(0);
        }
    }

    asm volatile("s_waitcnt vmcnt(0)" ::: "memory");

    if (z < 2) {
        unsigned short* outz = qkv + (size_t)z * NTOKn * Dn;
#pragma unroll
        for (int mf = 0; mf < 8; ++mf) {
            const int row = m0 + wm * 128 + mf * 16 + (l >> 4) * 4;
#pragma unroll
            for (int nf = 0; nf < 4; ++nf) {
                const int col = (n0 + wn * 64 + nf * 16 + (l & 15)) & 1023;
#pragma unroll
                for (int i = 0; i < 4; ++i)
                    outz[(size_t)(row + i) * Dn + col] = f2bf(acc[mf][nf][i] + biasv[nf]);
            }
        }
    } else {
        // V: write transposed vT[(b*1024 + col)][s], 4 consecutive s per lane
#pragma unroll
        for (int mf = 0; mf < 8; ++mf) {
            const int row = m0 + wm * 128 + mf * 16 + (l >> 4) * 4;
            const int b = row >> 11, s = row & 2047;
#pragma unroll
            for (int nf = 0; nf < 4; ++nf) {
                const int col = (n0 + wn * 64 + nf * 16 + (l & 15)) & 1023;
                ushort4 o;
                o.x = f2bf(acc[mf][nf][0] + biasv[nf]);
                o.y = f2bf(acc[mf][nf][1] + biasv[nf]);
                o.z = f2bf(acc[mf][nf][2] + biasv[nf]);
                o.w = f2bf(acc[mf][nf][3] + biasv[nf]);
                *reinterpret_cast<ushort4*>(vT + ((size_t)(b * 1024 + col)) * Sn + s) = o;
            }
        }
    }
}

// ---------------- bf16 GEMM (m97 structure, 128x128) for the out-projection ----------------
__global__ __launch_bounds__(256) void k_gemm_op(const unsigned short* __restrict__ A,
                                                 const unsigned short* __restrict__ Bt,
                                                 const float* __restrict__ bias,
                                                 float* __restrict__ C,
                                                 int M, int N, int K) {
    __shared__ unsigned short As[128][32];
    __shared__ unsigned short Bs[128][32];
    const int t = threadIdx.x;
    const int w = t >> 6, l = t & 63;
    const int m0 = blockIdx.x * 128, n0 = blockIdx.y * 128;
    const int wr = (w >> 1) * 64, wc = (w & 1) * 64;

    const int lrow = t >> 2;
    const int lcol = (t & 3) * 8;
    const unsigned short* gA = A + (size_t)(m0 + lrow) * K + lcol;
    const unsigned short* gB = Bt + (size_t)(n0 + lrow) * K + lcol;
    unsigned short* lA = &As[0][0] + t * 8;
    unsigned short* lB = &Bs[0][0] + t * 8;

    f32x4 acc[4][4] = {};

    for (int k0 = 0; k0 < K; k0 += 32) {
        __syncthreads();
        gll16(gA + k0, lA);
        gll16(gA + (size_t)64 * K + k0, lA + 2048);
        gll16(gB + k0, lB);
        gll16(gB + (size_t)64 * K + k0, lB + 2048);
        __syncthreads();

        bf16x8 af[4], bfv[4];
#pragma unroll
        for (int i = 0; i < 4; ++i)
            af[i] = *reinterpret_cast<const bf16x8*>(&As[wr + i * 16 + (l & 15)][(l >> 4) * 8]);
#pragma unroll
        for (int i = 0; i < 4; ++i)
            bfv[i] = *reinterpret_cast<const bf16x8*>(&Bs[wc + i * 16 + (l & 15)][(l >> 4) * 8]);
#pragma unroll
        for (int mi = 0; mi < 4; ++mi)
#pragma unroll
            for (int ni = 0; ni < 4; ++ni)
                acc[mi][ni] =
                    __builtin_amdgcn_mfma_f32_16x16x32_bf16(af[mi], bfv[ni], acc[mi][ni], 0, 0, 0);
    }

#pragma unroll
    for (int mi = 0; mi < 4; ++mi) {
        const int row = m0 + wr + mi * 16 + (l >> 4) * 4;
#pragma unroll
        for (int ni = 0; ni < 4; ++ni) {
            const int col = n0 + wc + ni * 16 + (l & 15);
            const float bv = bias[col];
#pragma unroll
            for (int i = 0; i < 4; ++i)
                C[(size_t)(row + i) * N + col] = acc[mi][ni][i] + bv;
        }
    }
}

// ---------------- fused attention: attn = relu(QK^T*scale), ctx = attn @ V ----------------
// R7 structure (empirical best). XCD-aware remap; plain cached attn stores
// issued AFTER the 8 global_load_lds of the next tile; counted vmcnt(63)
// retires the loads without draining the store backlog (T4); raw s_barrier +
// lgkm-only waits elsewhere; no vmcnt(0) anywhere in the loop.
__global__ __launch_bounds__(256, 2) void k_attn(const unsigned short* __restrict__ Qb,
                                                 const unsigned short* __restrict__ Kb,
                                                 const unsigned short* __restrict__ VTb,
                                                 float* __restrict__ attn,
                                                 unsigned short* __restrict__ ctx) {
    __shared__ unsigned short Ks[128 * 64];
    __shared__ unsigned short Vs[64 * 128];
    __shared__ unsigned short Ps[4][32][136];

    const int t = threadIdx.x;
    const int w = t >> 6, l = t & 63;

    // XCD-aware bijective remap (dispatch round-robins linear%8 across XCDs)
    const int lin = blockIdx.x + 16 * blockIdx.y;
    const int xcd = lin & 7, idx = lin >> 3;
    const int bh = xcd * 4 + (idx >> 4);
    const int q0 = (idx & 15) * 128;
    const int b = bh >> 4, h = bh & 15;
    const float scale = 0.125f;  // 1/sqrt(64)

    bf16x8 qf[2][2];
#pragma unroll
    for (int mi = 0; mi < 2; ++mi)
#pragma unroll
        for (int kk = 0; kk < 2; ++kk)
            qf[mi][kk] = *reinterpret_cast<const bf16x8*>(
                Qb + (size_t)(b * Sn + q0 + w * 32 + mi * 16 + (l & 15)) * Dn + h * DEP +
                kk * 32 + (l >> 4) * 8);

    const int krow = t >> 3;
    const int kcolswz = ((t & 7) * 8) ^ ((krow & 7) << 3);
    const int vrow = t >> 4;
    const int vcolswz = ((t & 15) * 8) ^ ((vrow & 7) << 3);
    unsigned short* lK = Ks + t * 8;
    unsigned short* lV = Vs + t * 8;

    f32x4 ctxa[2][4] = {};
    f32x4 sa[2][8];  // relu'd P for current tile; persists into next iter for store

    float* const abase = attn + (size_t)bh * Sn * Sn + (size_t)(q0 + w * 32) * Sn;

    auto STAGE = [&](int kb) {
#pragma unroll
        for (int is = 0; is < 4; ++is) {
            gll16(Kb + (size_t)(b * Sn + kb * 128 + is * 32 + krow) * Dn + h * DEP + kcolswz,
                  lK + is * 2048);
            gll16(VTb + (size_t)(bh * DEP + is * 16 + vrow) * Sn + kb * 128 + vcolswz,
                  lV + is * 2048);
        }
    };

    auto QKT = [&]() {
#pragma unroll
        for (int mi = 0; mi < 2; ++mi)
#pragma unroll
            for (int nj = 0; nj < 8; ++nj)
                sa[mi][nj] = (f32x4){0.f, 0.f, 0.f, 0.f};
#pragma unroll
        for (int nj = 0; nj < 8; ++nj) {
            const int kr = nj * 16 + (l & 15);
#pragma unroll
            for (int kk = 0; kk < 2; ++kk) {
                const int kidx = (kr * 64 + kk * 32 + (l >> 4) * 8) ^ ((kr & 7) << 3);
                const bf16x8 bfr = *reinterpret_cast<const bf16x8*>(Ks + kidx);
                sa[0][nj] = __builtin_amdgcn_mfma_f32_16x16x32_bf16(qf[0][kk], bfr, sa[0][nj], 0, 0, 0);
                sa[1][nj] = __builtin_amdgcn_mfma_f32_16x16x32_bf16(qf[1][kk], bfr, sa[1][nj], 0, 0, 0);
            }
        }
#pragma unroll
        for (int mi = 0; mi < 2; ++mi) {
#pragma unroll
            for (int nj = 0; nj < 8; ++nj) {
                f32x4 v = sa[mi][nj];
#pragma unroll
                for (int i = 0; i < 4; ++i) {
                    float p = v[i] * scale;
                    v[i] = p > 0.f ? p : 0.f;
                }
                sa[mi][nj] = v;
                const int kc = nj * 16 + (l & 15);
#pragma unroll
                for (int i = 0; i < 4; ++i)
                    Ps[w][mi * 16 + (l >> 4) * 4 + i][kc] = f2bf(v[i]);
            }
        }
    };

    auto PV = [&]() {
        bf16x8 pf[2][4];
#pragma unroll
        for (int mi = 0; mi < 2; ++mi)
#pragma unroll
            for (int kk = 0; kk < 4; ++kk)
                pf[mi][kk] = *reinterpret_cast<const bf16x8*>(
                    &Ps[w][mi * 16 + (l & 15)][kk * 32 + (l >> 4) * 8]);
#pragma unroll
        for (int nd = 0; nd < 4; ++nd) {
            const int vr = nd * 16 + (l & 15);
#pragma unroll
            for (int kk = 0; kk < 4; ++kk) {
                const int vidx = (vr * 128 + kk * 32 + (l >> 4) * 8) ^ ((vr & 7) << 3);
                const bf16x8 vfr = *reinterpret_cast<const bf16x8*>(Vs + vidx);
                ctxa[0][nd] = __builtin_amdgcn_mfma_f32_16x16x32_bf16(pf[0][kk], vfr, ctxa[0][nd], 0, 0, 0);
                ctxa[1][nd] = __builtin_amdgcn_mfma_f32_16x16x32_bf16(pf[1][kk], vfr, ctxa[1][nd], 0, 0, 0);
            }
        }
    };

    auto STORE_SA = [&](int kb) {  // plain cached stores from sa
        float* arow = abase + kb * 128;
#pragma unroll
        for (int mi = 0; mi < 2; ++mi)
#pragma unroll
            for (int nj = 0; nj < 8; ++nj) {
                const int kc = nj * 16 + (l & 15);
#pragma unroll
                for (int i = 0; i < 4; ++i)
                    arow[(size_t)(mi * 16 + (l >> 4) * 4 + i) * Sn + kc] = sa[mi][nj][i];
            }
    };

    STAGE(0);
    asm volatile("s_waitcnt vmcnt(0)" ::: "memory");
    __builtin_amdgcn_s_barrier();
    __builtin_amdgcn_sched_barrier(0);
    QKT();
    PV();

    for (int kb = 1; kb < Sn / 128; ++kb) {
        asm volatile("s_waitcnt lgkmcnt(0)" ::: "memory");
        __builtin_amdgcn_s_barrier();
        __builtin_amdgcn_sched_barrier(0);
        STAGE(kb);                             // 8 loads (oldest)
        asm volatile("" ::: "memory");         // keep stores after loads in issue order
        STORE_SA(kb - 1);                      // 64 stores (fire and forget)
        asm volatile("s_waitcnt vmcnt(63)" ::: "memory");  // loads retired, stores free
        __builtin_amdgcn_s_barrier();
        __builtin_amdgcn_sched_barrier(0);
        QKT();
        PV();
    }
    STORE_SA(Sn / 128 - 1);

#pragma unroll
    for (int mi = 0; mi < 2; ++mi) {
#pragma unroll
        for (int nd = 0; nd < 4; ++nd) {
            const int dc = nd * 16 + (l & 15);
#pragma unroll
            for (int i = 0; i < 4; ++i) {
                const int qr = q0 + w * 32 + mi * 16 + (l >> 4) * 4 + i;
                ctx[(size_t)(b * Sn + qr) * Dn + h * DEP + dc] = f2bf(ctxa[mi][nd][i]);
            }
        }
    }
}

extern "C" void kernel_launch(void* const* d_in, const int* in_sizes, int n_in,
                              void* d_out, int out_size, void* d_ws, size_t ws_size,
                              hipStream_t stream) {
    (void)in_sizes; (void)n_in; (void)out_size; (void)ws_size;
    const float* x  = (const float*)d_in[0];
    const float* wq = (const float*)d_in[1];
    const float* bq = (const float*)d_in[2];
    const float* wk = (const float*)d_in[3];
    const float* bk = (const float*)d_in[4];
    const float* wv = (const float*)d_in[5];
    const float* bv = (const float*)d_in[6];
    const float* wo = (const float*)d_in[7];
    const float* bo = (const float*)d_in[8];

    float* out  = (float*)d_out;
    float* attn = out + (size_t)Bn * Sn * Dn;  // outputs concatenated: (out, attn)

    char* ws = (char*)d_ws;
    unsigned short* xb = (unsigned short*)ws;  ws += (size_t)NTOKn * Dn * 2;       // 8 MB
    unsigned short* wT = (unsigned short*)ws;  ws += (size_t)4 * Dn * Dn * 2;      // 8 MB [q,k,v,o]
    unsigned short* qkv = (unsigned short*)ws; ws += (size_t)3 * NTOKn * Dn * 2;   // 24 MB (v third unused)
    unsigned short* vT = (unsigned short*)ws;  ws += (size_t)NTOKn * Dn * 2;       // 8 MB
    unsigned short* ctx = (unsigned short*)ws;                                     // 8 MB

    const size_t DD = (size_t)Dn * Dn;

    static bool attr_set = false;
    if (!attr_set) {
        hipFuncSetAttribute(reinterpret_cast<const void*>(k_qkv8),
                            hipFuncAttributeMaxDynamicSharedMemorySize, 131072);
        attr_set = true;
    }

    k_prep<<<dim3(5120), 256, 0, stream>>>(x, wq, wk, wv, wo, xb,
                                           wT, wT + DD, wT + 2 * DD, wT + 3 * DD);
    k_qkv8<<<dim3(16, 12), 512, 131072, stream>>>(xb, wT, bq, bk, bv, qkv, vT);
    k_attn<<<dim3(16, 32), 256, 0, stream>>>(qkv, qkv + (size_t)NTOKn * Dn, vT, attn, ctx);
    k_gemm_op<<<dim3(32, 8), 256, 0, stream>>>(ctx, wT + 3 * DD, bo, out, NTOKn, Dn, Dn);
}

// Round 14
// 213.027 us; speedup vs baseline: 1.2473x; 1.0057x over previous
//
#include <hip/hip_runtime.h>
#include <hip/hip_bf16.h>

// Problem constants (reference: B=2, S=2048, D=1024, H=16, DEPTH=64)
constexpr int Bn = 2, Sn = 2048, Dn = 1024, Hn = 16, DEP = 64;
constexpr int NTOKn = Bn * Sn;  // 4096 rows for the token-dim GEMMs

typedef __bf16 bf16x8 __attribute__((ext_vector_type(8)));
typedef float f32x4 __attribute__((ext_vector_type(4)));

__device__ __forceinline__ unsigned short f2bf(float f) {
    union { __hip_bfloat16 h; unsigned short u; } cv;
    cv.h = __float2bfloat16(f);
    return cv.u;
}

// async global->LDS, 16B per lane. LDS dest must be wave-uniform base + lane*16.
__device__ __forceinline__ void gll16(const void* g, void* l) {
    __builtin_amdgcn_global_load_lds(
        (const __attribute__((address_space(1))) unsigned int*)g,
        (__attribute__((address_space(3))) unsigned int*)l, 16, 0, 0);
}

// ---------------- fused prep: x f32->bf16 convert + 4x weight transpose ----------------
__global__ __launch_bounds__(256) void k_prep(const float* __restrict__ x,
                                              const float* __restrict__ w0,
                                              const float* __restrict__ w1,
                                              const float* __restrict__ w2,
                                              const float* __restrict__ w3,
                                              unsigned short* __restrict__ xb,
                                              unsigned short* __restrict__ t0,
                                              unsigned short* __restrict__ t1,
                                              unsigned short* __restrict__ t2,
                                              unsigned short* __restrict__ t3) {
    const int bid = blockIdx.x;
    const int t = threadIdx.x;
    if (bid < 4096) {
        const int idx = (bid * 256 + t) * 4;
        float4 v = *reinterpret_cast<const float4*>(x + idx);
        ushort4 o;
        o.x = f2bf(v.x); o.y = f2bf(v.y); o.z = f2bf(v.z); o.w = f2bf(v.w);
        *reinterpret_cast<ushort4*>(xb + idx) = o;
        return;
    }
    const int b2 = bid - 4096;
    const float* w; unsigned short* tp;
    switch (b2 >> 8) {
        case 0: w = w0; tp = t0; break;
        case 1: w = w1; tp = t1; break;
        case 2: w = w2; tp = t2; break;
        default: w = w3; tp = t3; break;
    }
    __shared__ unsigned short tile[64][65];
    const int k0 = ((b2 & 255) >> 4) * 64, n0 = (b2 & 15) * 64;
    const int c = t & 63, rb = t >> 6;
#pragma unroll
    for (int i = 0; i < 16; ++i) {
        int r = rb + i * 4;
        tile[r][c] = f2bf(w[(size_t)(k0 + r) * Dn + n0 + c]);
    }
    __syncthreads();
#pragma unroll
    for (int i = 0; i < 16; ++i) {
        int n = rb + i * 4;
        tp[(size_t)(n0 + n) * Dn + k0 + c] = tile[c][n];
    }
}

// =================== QKV GEMM, 8-phase-style 256x256 tile ===================
// (counted vmcnt(4), T2 slot-swizzle, T5 setprio)
// Epilogue: Q/K blocks write qkv[z][token][dim]; V blocks (z==2) write the
// TRANSPOSED vT[(b*1024+col)][s] directly as ushort4.
__global__ __launch_bounds__(512, 2) void k_qkv8(const unsigned short* __restrict__ A,
                                                 const unsigned short* __restrict__ Bt,
                                                 const float* __restrict__ bq,
                                                 const float* __restrict__ bk,
                                                 const float* __restrict__ bv,
                                                 unsigned short* __restrict__ qkv,
                                                 unsigned short* __restrict__ vT) {
    extern __shared__ char smem[];  // 131072 bytes
    constexpr int K = 1024, NT = K / 64;  // 16 K-steps

    const int t = threadIdx.x;
    const int w = t >> 6, l = t & 63;
    const int wm = w >> 2, wn = w & 3;
    const int m0 = blockIdx.x * 256;
    const int n0 = blockIdx.y * 256;
    const int z = n0 >> 10;

    const float* bias = (z == 0) ? bq : (z == 1 ? bk : bv);
    float biasv[4];
#pragma unroll
    for (int nf = 0; nf < 4; ++nf)
        biasv[nf] = bias[(n0 + wn * 64 + nf * 16 + (l & 15)) & 1023];

    int aoff[2], boff[2], ldsoff[2];
#pragma unroll
    for (int i = 0; i < 2; ++i) {
        const int idx = i * 512 + t;
        const int row = idx >> 2;
        const int s = ((idx & 3) - row - (row >> 2)) & 3;
        aoff[i] = (m0 + row) * K + s * 8;
        boff[i] = (n0 + row) * K + s * 8;
        ldsoff[i] = idx * 16;
    }

    f32x4 acc[8][4] = {};

#pragma unroll
    for (int kh = 0; kh < 2; ++kh) {
        if (kh == 0) {
#pragma unroll
            for (int i = 0; i < 2; ++i) gll16(A + aoff[i], smem + ldsoff[i]);
#pragma unroll
            for (int i = 0; i < 2; ++i) gll16(Bt + boff[i], smem + 65536 + ldsoff[i]);
        } else {
#pragma unroll
            for (int i = 0; i < 2; ++i) gll16(A + aoff[i] + 32, smem + 16384 + ldsoff[i]);
#pragma unroll
            for (int i = 0; i < 2; ++i) gll16(Bt + boff[i] + 32, smem + 65536 + 16384 + ldsoff[i]);
        }
    }

    for (int kb = 0; kb < NT; ++kb) {
        const int c = kb & 1;
        const int kn = (kb + 1 < NT) ? kb + 1 : NT - 1;
        const int cn = c ^ 1;
        const int Abase = c * 32768;
        const int Bbase = 65536 + c * 32768;
        const int AbaseN = cn * 32768;
        const int BbaseN = 65536 + cn * 32768;

        bf16x8 bf[4], af[4];

#pragma unroll
        for (int ph = 0; ph < 4; ++ph) {
            const int kk = ph >> 1;
            const int mb = (ph & 1) * 4;

            if ((ph & 1) == 0) {
                asm volatile("s_waitcnt vmcnt(4)" ::: "memory");
            }
            __builtin_amdgcn_s_barrier();
            __builtin_amdgcn_sched_barrier(0);

            if ((ph & 1) == 0) {
#pragma unroll
                for (int nf = 0; nf < 4; ++nf) {
                    const int row = wn * 64 + nf * 16 + (l & 15);
                    const int byte = Bbase + kk * 16384 + row * 64 +
                                     ((((l >> 4) + row + (row >> 2)) & 3) * 16);
                    bf[nf] = *reinterpret_cast<const bf16x8*>(smem + byte);
                }
            }
#pragma unroll
            for (int mfl = 0; mfl < 4; ++mfl) {
                const int row = wm * 128 + (mb + mfl) * 16 + (l & 15);
                const int byte = Abase + kk * 16384 + row * 64 +
                                 ((((l >> 4) + row + (row >> 2)) & 3) * 16);
                af[mfl] = *reinterpret_cast<const bf16x8*>(smem + byte);
            }

            {
                const int khs = ph >> 1;
                if ((ph & 1) == 0) {
#pragma unroll
                    for (int i = 0; i < 2; ++i)
                        gll16(A + aoff[i] + kn * 64 + khs * 32,
                              smem + AbaseN + khs * 16384 + ldsoff[i]);
                } else {
#pragma unroll
                    for (int i = 0; i < 2; ++i)
                        gll16(Bt + boff[i] + kn * 64 + khs * 32,
                              smem + BbaseN + khs * 16384 + ldsoff[i]);
                }
            }

            asm volatile("s_waitcnt lgkmcnt(0)" ::: "memory");
            __builtin_amdgcn_sched_barrier(0);
            __builtin_amdgcn_s_setprio(1);
#pragma unroll
            for (int mfl = 0; mfl < 4; ++mfl)
#pragma unroll
                for (int nf = 0; nf < 4; ++nf)
                    acc[mb + mfl][nf] = __builtin_amdgcn_mfma_f32_16x16x32_bf16(
                        af[mfl], bf[nf], acc[mb + mfl][nf], 0, 0, 0);
            __builtin_amdgcn_s_setprio(0);
        }
    }

    asm volatile("s_waitcnt vmcnt(0)" ::: "memory");

    if (z < 2) {
        unsigned short* outz = qkv + (size_t)z * NTOKn * Dn;
#pragma unroll
        for (int mf = 0; mf < 8; ++mf) {
            const int row = m0 + wm * 128 + mf * 16 + (l >> 4) * 4;
#pragma unroll
            for (int nf = 0; nf < 4; ++nf) {
                const int col = (n0 + wn * 64 + nf * 16 + (l & 15)) & 1023;
#pragma unroll
                for (int i = 0; i < 4; ++i)
                    outz[(size_t)(row + i) * Dn + col] = f2bf(acc[mf][nf][i] + biasv[nf]);
            }
        }
    } else {
        // V: write transposed vT[(b*1024 + col)][s], 4 consecutive s per lane
#pragma unroll
        for (int mf = 0; mf < 8; ++mf) {
            const int row = m0 + wm * 128 + mf * 16 + (l >> 4) * 4;
            const int b = row >> 11, s = row & 2047;
#pragma unroll
            for (int nf = 0; nf < 4; ++nf) {
                const int col = (n0 + wn * 64 + nf * 16 + (l & 15)) & 1023;
                ushort4 o;
                o.x = f2bf(acc[mf][nf][0] + biasv[nf]);
                o.y = f2bf(acc[mf][nf][1] + biasv[nf]);
                o.z = f2bf(acc[mf][nf][2] + biasv[nf]);
                o.w = f2bf(acc[mf][nf][3] + biasv[nf]);
                *reinterpret_cast<ushort4*>(vT + ((size_t)(b * 1024 + col)) * Sn + s) = o;
            }
        }
    }
}

// ---------------- bf16 GEMM (m97 structure, 128x128) for the out-projection ----------------
__global__ __launch_bounds__(256) void k_gemm_op(const unsigned short* __restrict__ A,
                                                 const unsigned short* __restrict__ Bt,
                                                 const float* __restrict__ bias,
                                                 float* __restrict__ C,
                                                 int M, int N, int K) {
    __shared__ unsigned short As[128][32];
    __shared__ unsigned short Bs[128][32];
    const int t = threadIdx.x;
    const int w = t >> 6, l = t & 63;
    const int m0 = blockIdx.x * 128, n0 = blockIdx.y * 128;
    const int wr = (w >> 1) * 64, wc = (w & 1) * 64;

    const int lrow = t >> 2;
    const int lcol = (t & 3) * 8;
    const unsigned short* gA = A + (size_t)(m0 + lrow) * K + lcol;
    const unsigned short* gB = Bt + (size_t)(n0 + lrow) * K + lcol;
    unsigned short* lA = &As[0][0] + t * 8;
    unsigned short* lB = &Bs[0][0] + t * 8;

    f32x4 acc[4][4] = {};

    for (int k0 = 0; k0 < K; k0 += 32) {
        __syncthreads();
        gll16(gA + k0, lA);
        gll16(gA + (size_t)64 * K + k0, lA + 2048);
        gll16(gB + k0, lB);
        gll16(gB + (size_t)64 * K + k0, lB + 2048);
        __syncthreads();

        bf16x8 af[4], bfv[4];
#pragma unroll
        for (int i = 0; i < 4; ++i)
            af[i] = *reinterpret_cast<const bf16x8*>(&As[wr + i * 16 + (l & 15)][(l >> 4) * 8]);
#pragma unroll
        for (int i = 0; i < 4; ++i)
            bfv[i] = *reinterpret_cast<const bf16x8*>(&Bs[wc + i * 16 + (l & 15)][(l >> 4) * 8]);
#pragma unroll
        for (int mi = 0; mi < 4; ++mi)
#pragma unroll
            for (int ni = 0; ni < 4; ++ni)
                acc[mi][ni] =
                    __builtin_amdgcn_mfma_f32_16x16x32_bf16(af[mi], bfv[ni], acc[mi][ni], 0, 0, 0);
    }

#pragma unroll
    for (int mi = 0; mi < 4; ++mi) {
        const int row = m0 + wr + mi * 16 + (l >> 4) * 4;
#pragma unroll
        for (int ni = 0; ni < 4; ++ni) {
            const int col = n0 + wc + ni * 16 + (l & 15);
            const float bv = bias[col];
#pragma unroll
            for (int i = 0; i < 4; ++i)
                C[(size_t)(row + i) * N + col] = acc[mi][ni][i] + bv;
        }
    }
}

// ---------------- fused attention: attn = relu(QK^T*scale), ctx = attn @ V ----------------
// R7 structure (empirical best). XCD-aware remap; plain cached attn stores
// issued AFTER the 8 global_load_lds of the next tile; counted vmcnt(63)
// retires the loads without draining the store backlog (T4); raw s_barrier +
// lgkm-only waits elsewhere; no vmcnt(0) anywhere in the loop.
__global__ __launch_bounds__(256, 2) void k_attn(const unsigned short* __restrict__ Qb,
                                                 const unsigned short* __restrict__ Kb,
                                                 const unsigned short* __restrict__ VTb,
                                                 float* __restrict__ attn,
                                                 unsigned short* __restrict__ ctx) {
    __shared__ unsigned short Ks[128 * 64];
    __shared__ unsigned short Vs[64 * 128];
    __shared__ unsigned short Ps[4][32][136];

    const int t = threadIdx.x;
    const int w = t >> 6, l = t & 63;

    // XCD-aware bijective remap (dispatch round-robins linear%8 across XCDs)
    const int lin = blockIdx.x + 16 * blockIdx.y;
    const int xcd = lin & 7, idx = lin >> 3;
    const int bh = xcd * 4 + (idx >> 4);
    const int q0 = (idx & 15) * 128;
    const int b = bh >> 4, h = bh & 15;
    const float scale = 0.125f;  // 1/sqrt(64)

    bf16x8 qf[2][2];
#pragma unroll
    for (int mi = 0; mi < 2; ++mi)
#pragma unroll
        for (int kk = 0; kk < 2; ++kk)
            qf[mi][kk] = *reinterpret_cast<const bf16x8*>(
                Qb + (size_t)(b * Sn + q0 + w * 32 + mi * 16 + (l & 15)) * Dn + h * DEP +
                kk * 32 + (l >> 4) * 8);

    const int krow = t >> 3;
    const int kcolswz = ((t & 7) * 8) ^ ((krow & 7) << 3);
    const int vrow = t >> 4;
    const int vcolswz = ((t & 15) * 8) ^ ((vrow & 7) << 3);
    unsigned short* lK = Ks + t * 8;
    unsigned short* lV = Vs + t * 8;

    f32x4 ctxa[2][4] = {};
    f32x4 sa[2][8];  // relu'd P for current tile; persists into next iter for store

    float* const abase = attn + (size_t)bh * Sn * Sn + (size_t)(q0 + w * 32) * Sn;

    auto STAGE = [&](int kb) {
#pragma unroll
        for (int is = 0; is < 4; ++is) {
            gll16(Kb + (size_t)(b * Sn + kb * 128 + is * 32 + krow) * Dn + h * DEP + kcolswz,
                  lK + is * 2048);
            gll16(VTb + (size_t)(bh * DEP + is * 16 + vrow) * Sn + kb * 128 + vcolswz,
                  lV + is * 2048);
        }
    };

    auto QKT = [&]() {
#pragma unroll
        for (int mi = 0; mi < 2; ++mi)
#pragma unroll
            for (int nj = 0; nj < 8; ++nj)
                sa[mi][nj] = (f32x4){0.f, 0.f, 0.f, 0.f};
#pragma unroll
        for (int nj = 0; nj < 8; ++nj) {
            const int kr = nj * 16 + (l & 15);
#pragma unroll
            for (int kk = 0; kk < 2; ++kk) {
                const int kidx = (kr * 64 + kk * 32 + (l >> 4) * 8) ^ ((kr & 7) << 3);
                const bf16x8 bfr = *reinterpret_cast<const bf16x8*>(Ks + kidx);
                sa[0][nj] = __builtin_amdgcn_mfma_f32_16x16x32_bf16(qf[0][kk], bfr, sa[0][nj], 0, 0, 0);
                sa[1][nj] = __builtin_amdgcn_mfma_f32_16x16x32_bf16(qf[1][kk], bfr, sa[1][nj], 0, 0, 0);
            }
        }
#pragma unroll
        for (int mi = 0; mi < 2; ++mi) {
#pragma unroll
            for (int nj = 0; nj < 8; ++nj) {
                f32x4 v = sa[mi][nj];
#pragma unroll
                for (int i = 0; i < 4; ++i) {
                    float p = v[i] * scale;
                    v[i] = p > 0.f ? p : 0.f;
                }
                sa[mi][nj] = v;
                const int kc = nj * 16 + (l & 15);
#pragma unroll
                for (int i = 0; i < 4; ++i)
                    Ps[w][mi * 16 + (l >> 4) * 4 + i][kc] = f2bf(v[i]);
            }
        }
    };

    auto PV = [&]() {
        bf16x8 pf[2][4];
#pragma unroll
        for (int mi = 0; mi < 2; ++mi)
#pragma unroll
            for (int kk = 0; kk < 4; ++kk)
                pf[mi][kk] = *reinterpret_cast<const bf16x8*>(
                    &Ps[w][mi * 16 + (l & 15)][kk * 32 + (l >> 4) * 8]);
#pragma unroll
        for (int nd = 0; nd < 4; ++nd) {
            const int vr = nd * 16 + (l & 15);
#pragma unroll
            for (int kk = 0; kk < 4; ++kk) {
                const int vidx = (vr * 128 + kk * 32 + (l >> 4) * 8) ^ ((vr & 7) << 3);
                const bf16x8 vfr = *reinterpret_cast<const bf16x8*>(Vs + vidx);
                ctxa[0][nd] = __builtin_amdgcn_mfma_f32_16x16x32_bf16(pf[0][kk], vfr, ctxa[0][nd], 0, 0, 0);
                ctxa[1][nd] = __builtin_amdgcn_mfma_f32_16x16x32_bf16(pf[1][kk], vfr, ctxa[1][nd], 0, 0, 0);
            }
        }
    };

    auto STORE_SA = [&](int kb) {  // plain cached stores from sa
        float* arow = abase + kb * 128;
#pragma unroll
        for (int mi = 0; mi < 2; ++mi)
#pragma unroll
            for (int nj = 0; nj < 8; ++nj) {
                const int kc = nj * 16 + (l & 15);
#pragma unroll
                for (int i = 0; i < 4; ++i)
                    arow[(size_t)(mi * 16 + (l >> 4) * 4 + i) * Sn + kc] = sa[mi][nj][i];
            }
    };

    STAGE(0);
    asm volatile("s_waitcnt vmcnt(0)" ::: "memory");
    __builtin_amdgcn_s_barrier();
    __builtin_amdgcn_sched_barrier(0);
    QKT();
    PV();

    for (int kb = 1; kb < Sn / 128; ++kb) {
        asm volatile("s_waitcnt lgkmcnt(0)" ::: "memory");
        __builtin_amdgcn_s_barrier();
        __builtin_amdgcn_sched_barrier(0);
        STAGE(kb);                             // 8 loads (oldest)
        asm volatile("" ::: "memory");         // keep stores after loads in issue order
        STORE_SA(kb - 1);                      // 64 stores (fire and forget)
        asm volatile("s_waitcnt vmcnt(63)" ::: "memory");  // loads retired, stores free
        __builtin_amdgcn_s_barrier();
        __builtin_amdgcn_sched_barrier(0);
        QKT();
        PV();
    }
    STORE_SA(Sn / 128 - 1);

#pragma unroll
    for (int mi = 0; mi < 2; ++mi) {
#pragma unroll
        for (int nd = 0; nd < 4; ++nd) {
            const int dc = nd * 16 + (l & 15);
#pragma unroll
            for (int i = 0; i < 4; ++i) {
                const int qr = q0 + w * 32 + mi * 16 + (l >> 4) * 4 + i;
                ctx[(size_t)(b * Sn + qr) * Dn + h * DEP + dc] = f2bf(ctxa[mi][nd][i]);
            }
        }
    }
}

extern "C" void kernel_launch(void* const* d_in, const int* in_sizes, int n_in,
                              void* d_out, int out_size, void* d_ws, size_t ws_size,
                              hipStream_t stream) {
    (void)in_sizes; (void)n_in; (void)out_size; (void)ws_size;
    const float* x  = (const float*)d_in[0];
    const float* wq = (const float*)d_in[1];
    const float* bq = (const float*)d_in[2];
    const float* wk = (const float*)d_in[3];
    const float* bk = (const float*)d_in[4];
    const float* wv = (const float*)d_in[5];
    const float* bv = (const float*)d_in[6];
    const float* wo = (const float*)d_in[7];
    const float* bo = (const float*)d_in[8];

    float* out  = (float*)d_out;
    float* attn = out + (size_t)Bn * Sn * Dn;  // outputs concatenated: (out, attn)

    char* ws = (char*)d_ws;
    unsigned short* xb = (unsigned short*)ws;  ws += (size_t)NTOKn * Dn * 2;       // 8 MB
    unsigned short* wT = (unsigned short*)ws;  ws += (size_t)4 * Dn * Dn * 2;      // 8 MB [q,k,v,o]
    unsigned short* qkv = (unsigned short*)ws; ws += (size_t)3 * NTOKn * Dn * 2;   // 24 MB (v third unused)
    unsigned short* vT = (unsigned short*)ws;  ws += (size_t)NTOKn * Dn * 2;       // 8 MB
    unsigned short* ctx = (unsigned short*)ws;                                     // 8 MB

    const size_t DD = (size_t)Dn * Dn;

    static bool attr_set = false;
    if (!attr_set) {
        hipFuncSetAttribute(reinterpret_cast<const void*>(k_qkv8),
                            hipFuncAttributeMaxDynamicSharedMemorySize, 131072);
        attr_set = true;
    }

    k_prep<<<dim3(5120), 256, 0, stream>>>(x, wq, wk, wv, wo, xb,
                                           wT, wT + DD, wT + 2 * DD, wT + 3 * DD);
    k_qkv8<<<dim3(16, 12), 512, 131072, stream>>>(xb, wT, bq, bk, bv, qkv, vT);
    k_attn<<<dim3(16, 32), 256, 0, stream>>>(qkv, qkv + (size_t)NTOKn * Dn, vT, attn, ctx);
    k_gemm_op<<<dim3(32, 8), 256, 0, stream>>>(ctx, wT + 3 * DD, bo, out, NTOKn, Dn, Dn);
}

// Round 15
// 198.221 us; speedup vs baseline: 1.3404x; 1.0747x over previous
//
#include <hip/hip_runtime.h>
#include <hip/hip_bf16.h>

// Problem constants (reference: B=2, S=2048, D=1024, H=16, DEPTH=64)
constexpr int Bn = 2, Sn = 2048, Dn = 1024, Hn = 16, DEP = 64;
constexpr int NTOKn = Bn * Sn;  // 4096 rows for the token-dim GEMMs

typedef __bf16 bf16x8 __attribute__((ext_vector_type(8)));
typedef float f32x4 __attribute__((ext_vector_type(4)));

__device__ __forceinline__ unsigned short f2bf(float f) {
    union { __hip_bfloat16 h; unsigned short u; } cv;
    cv.h = __float2bfloat16(f);
    return cv.u;
}

// async global->LDS, 16B per lane. LDS dest must be wave-uniform base + lane*16.
__device__ __forceinline__ void gll16(const void* g, void* l) {
    __builtin_amdgcn_global_load_lds(
        (const __attribute__((address_space(1))) unsigned int*)g,
        (__attribute__((address_space(3))) unsigned int*)l, 16, 0, 0);
}

// ---------------- fused prep: x f32->bf16 convert + 4x weight transpose ----------------
__global__ __launch_bounds__(256) void k_prep(const float* __restrict__ x,
                                              const float* __restrict__ w0,
                                              const float* __restrict__ w1,
                                              const float* __restrict__ w2,
                                              const float* __restrict__ w3,
                                              unsigned short* __restrict__ xb,
                                              unsigned short* __restrict__ t0,
                                              unsigned short* __restrict__ t1,
                                              unsigned short* __restrict__ t2,
                                              unsigned short* __restrict__ t3) {
    const int bid = blockIdx.x;
    const int t = threadIdx.x;
    if (bid < 4096) {
        const int idx = (bid * 256 + t) * 4;
        float4 v = *reinterpret_cast<const float4*>(x + idx);
        ushort4 o;
        o.x = f2bf(v.x); o.y = f2bf(v.y); o.z = f2bf(v.z); o.w = f2bf(v.w);
        *reinterpret_cast<ushort4*>(xb + idx) = o;
        return;
    }
    const int b2 = bid - 4096;
    const float* w; unsigned short* tp;
    switch (b2 >> 8) {
        case 0: w = w0; tp = t0; break;
        case 1: w = w1; tp = t1; break;
        case 2: w = w2; tp = t2; break;
        default: w = w3; tp = t3; break;
    }
    __shared__ unsigned short tile[64][65];
    const int k0 = ((b2 & 255) >> 4) * 64, n0 = (b2 & 15) * 64;
    const int c = t & 63, rb = t >> 6;
#pragma unroll
    for (int i = 0; i < 16; ++i) {
        int r = rb + i * 4;
        tile[r][c] = f2bf(w[(size_t)(k0 + r) * Dn + n0 + c]);
    }
    __syncthreads();
#pragma unroll
    for (int i = 0; i < 16; ++i) {
        int n = rb + i * 4;
        tp[(size_t)(n0 + n) * Dn + k0 + c] = tile[c][n];
    }
}

// =================== QKV GEMM, 8-phase-style 256x256 tile ===================
// (counted vmcnt(4), T2 slot-swizzle, T5 setprio)
// Epilogue: Q/K blocks write qkv[z][token][dim]; V blocks (z==2) write the
// TRANSPOSED vT[(b*1024+col)][s] directly as ushort4.
__global__ __launch_bounds__(512, 2) void k_qkv8(const unsigned short* __restrict__ A,
                                                 const unsigned short* __restrict__ Bt,
                                                 const float* __restrict__ bq,
                                                 const float* __restrict__ bk,
                                                 const float* __restrict__ bv,
                                                 unsigned short* __restrict__ qkv,
                                                 unsigned short* __restrict__ vT) {
    extern __shared__ char smem[];  // 131072 bytes
    constexpr int K = 1024, NT = K / 64;  // 16 K-steps

    const int t = threadIdx.x;
    const int w = t >> 6, l = t & 63;
    const int wm = w >> 2, wn = w & 3;
    const int m0 = blockIdx.x * 256;
    const int n0 = blockIdx.y * 256;
    const int z = n0 >> 10;

    const float* bias = (z == 0) ? bq : (z == 1 ? bk : bv);
    float biasv[4];
#pragma unroll
    for (int nf = 0; nf < 4; ++nf)
        biasv[nf] = bias[(n0 + wn * 64 + nf * 16 + (l & 15)) & 1023];

    int aoff[2], boff[2], ldsoff[2];
#pragma unroll
    for (int i = 0; i < 2; ++i) {
        const int idx = i * 512 + t;
        const int row = idx >> 2;
        const int s = ((idx & 3) - row - (row >> 2)) & 3;
        aoff[i] = (m0 + row) * K + s * 8;
        boff[i] = (n0 + row) * K + s * 8;
        ldsoff[i] = idx * 16;
    }

    f32x4 acc[8][4] = {};

#pragma unroll
    for (int kh = 0; kh < 2; ++kh) {
        if (kh == 0) {
#pragma unroll
            for (int i = 0; i < 2; ++i) gll16(A + aoff[i], smem + ldsoff[i]);
#pragma unroll
            for (int i = 0; i < 2; ++i) gll16(Bt + boff[i], smem + 65536 + ldsoff[i]);
        } else {
#pragma unroll
            for (int i = 0; i < 2; ++i) gll16(A + aoff[i] + 32, smem + 16384 + ldsoff[i]);
#pragma unroll
            for (int i = 0; i < 2; ++i) gll16(Bt + boff[i] + 32, smem + 65536 + 16384 + ldsoff[i]);
        }
    }

    for (int kb = 0; kb < NT; ++kb) {
        const int c = kb & 1;
        const int kn = (kb + 1 < NT) ? kb + 1 : NT - 1;
        const int cn = c ^ 1;
        const int Abase = c * 32768;
        const int Bbase = 65536 + c * 32768;
        const int AbaseN = cn * 32768;
        const int BbaseN = 65536 + cn * 32768;

        bf16x8 bf[4], af[4];

#pragma unroll
        for (int ph = 0; ph < 4; ++ph) {
            const int kk = ph >> 1;
            const int mb = (ph & 1) * 4;

            if ((ph & 1) == 0) {
                asm volatile("s_waitcnt vmcnt(4)" ::: "memory");
            }
            __builtin_amdgcn_s_barrier();
            __builtin_amdgcn_sched_barrier(0);

            if ((ph & 1) == 0) {
#pragma unroll
                for (int nf = 0; nf < 4; ++nf) {
                    const int row = wn * 64 + nf * 16 + (l & 15);
                    const int byte = Bbase + kk * 16384 + row * 64 +
                                     ((((l >> 4) + row + (row >> 2)) & 3) * 16);
                    bf[nf] = *reinterpret_cast<const bf16x8*>(smem + byte);
                }
            }
#pragma unroll
            for (int mfl = 0; mfl < 4; ++mfl) {
                const int row = wm * 128 + (mb + mfl) * 16 + (l & 15);
                const int byte = Abase + kk * 16384 + row * 64 +
                                 ((((l >> 4) + row + (row >> 2)) & 3) * 16);
                af[mfl] = *reinterpret_cast<const bf16x8*>(smem + byte);
            }

            {
                const int khs = ph >> 1;
                if ((ph & 1) == 0) {
#pragma unroll
                    for (int i = 0; i < 2; ++i)
                        gll16(A + aoff[i] + kn * 64 + khs * 32,
                              smem + AbaseN + khs * 16384 + ldsoff[i]);
                } else {
#pragma unroll
                    for (int i = 0; i < 2; ++i)
                        gll16(Bt + boff[i] + kn * 64 + khs * 32,
                              smem + BbaseN + khs * 16384 + ldsoff[i]);
                }
            }

            asm volatile("s_waitcnt lgkmcnt(0)" ::: "memory");
            __builtin_amdgcn_sched_barrier(0);
            __builtin_amdgcn_s_setprio(1);
#pragma unroll
            for (int mfl = 0; mfl < 4; ++mfl)
#pragma unroll
                for (int nf = 0; nf < 4; ++nf)
                    acc[mb + mfl][nf] = __builtin_amdgcn_mfma_f32_16x16x32_bf16(
                        af[mfl], bf[nf], acc[mb + mfl][nf], 0, 0, 0);
            __builtin_amdgcn_s_setprio(0);
        }
    }

    asm volatile("s_waitcnt vmcnt(0)" ::: "memory");

    if (z < 2) {
        unsigned short* outz = qkv + (size_t)z * NTOKn * Dn;
#pragma unroll
        for (int mf = 0; mf < 8; ++mf) {
            const int row = m0 + wm * 128 + mf * 16 + (l >> 4) * 4;
#pragma unroll
            for (int nf = 0; nf < 4; ++nf) {
                const int col = (n0 + wn * 64 + nf * 16 + (l & 15)) & 1023;
#pragma unroll
                for (int i = 0; i < 4; ++i)
                    outz[(size_t)(row + i) * Dn + col] = f2bf(acc[mf][nf][i] + biasv[nf]);
            }
        }
    } else {
        // V: write transposed vT[(b*1024 + col)][s], 4 consecutive s per lane
#pragma unroll
        for (int mf = 0; mf < 8; ++mf) {
            const int row = m0 + wm * 128 + mf * 16 + (l >> 4) * 4;
            const int b = row >> 11, s = row & 2047;
#pragma unroll
            for (int nf = 0; nf < 4; ++nf) {
                const int col = (n0 + wn * 64 + nf * 16 + (l & 15)) & 1023;
                ushort4 o;
                o.x = f2bf(acc[mf][nf][0] + biasv[nf]);
                o.y = f2bf(acc[mf][nf][1] + biasv[nf]);
                o.z = f2bf(acc[mf][nf][2] + biasv[nf]);
                o.w = f2bf(acc[mf][nf][3] + biasv[nf]);
                *reinterpret_cast<ushort4*>(vT + ((size_t)(b * 1024 + col)) * Sn + s) = o;
            }
        }
    }
}

// ---------------- bf16 GEMM (m97 structure, 128x128) for the out-projection ----------------
__global__ __launch_bounds__(256) void k_gemm_op(const unsigned short* __restrict__ A,
                                                 const unsigned short* __restrict__ Bt,
                                                 const float* __restrict__ bias,
                                                 float* __restrict__ C,
                                                 int M, int N, int K) {
    __shared__ unsigned short As[128][32];
    __shared__ unsigned short Bs[128][32];
    const int t = threadIdx.x;
    const int w = t >> 6, l = t & 63;
    const int m0 = blockIdx.x * 128, n0 = blockIdx.y * 128;
    const int wr = (w >> 1) * 64, wc = (w & 1) * 64;

    const int lrow = t >> 2;
    const int lcol = (t & 3) * 8;
    const unsigned short* gA = A + (size_t)(m0 + lrow) * K + lcol;
    const unsigned short* gB = Bt + (size_t)(n0 + lrow) * K + lcol;
    unsigned short* lA = &As[0][0] + t * 8;
    unsigned short* lB = &Bs[0][0] + t * 8;

    f32x4 acc[4][4] = {};

    for (int k0 = 0; k0 < K; k0 += 32) {
        __syncthreads();
        gll16(gA + k0, lA);
        gll16(gA + (size_t)64 * K + k0, lA + 2048);
        gll16(gB + k0, lB);
        gll16(gB + (size_t)64 * K + k0, lB + 2048);
        __syncthreads();

        bf16x8 af[4], bfv[4];
#pragma unroll
        for (int i = 0; i < 4; ++i)
            af[i] = *reinterpret_cast<const bf16x8*>(&As[wr + i * 16 + (l & 15)][(l >> 4) * 8]);
#pragma unroll
        for (int i = 0; i < 4; ++i)
            bfv[i] = *reinterpret_cast<const bf16x8*>(&Bs[wc + i * 16 + (l & 15)][(l >> 4) * 8]);
#pragma unroll
        for (int mi = 0; mi < 4; ++mi)
#pragma unroll
            for (int ni = 0; ni < 4; ++ni)
                acc[mi][ni] =
                    __builtin_amdgcn_mfma_f32_16x16x32_bf16(af[mi], bfv[ni], acc[mi][ni], 0, 0, 0);
    }

#pragma unroll
    for (int mi = 0; mi < 4; ++mi) {
        const int row = m0 + wr + mi * 16 + (l >> 4) * 4;
#pragma unroll
        for (int ni = 0; ni < 4; ++ni) {
            const int col = n0 + wc + ni * 16 + (l & 15);
            const float bv = bias[col];
#pragma unroll
            for (int i = 0; i < 4; ++i)
                C[(size_t)(row + i) * N + col] = acc[mi][ni][i] + bv;
        }
    }
}

// ---------------- fused attention: attn = relu(QK^T*scale), ctx = attn @ V ----------------
// R10 structure with ONE change: the 16 full-line dwordx4 attn stores are
// NON-TEMPORAL (no L2 allocate). Every store covers aligned 128B lines, so
// no-allocate incurs no partial-line RMW, and the 537 MB store stream no
// longer washes K/V out of each XCD's L2 (the XCD remap keeps the 2 MB K/V
// working set resident). Counted vmcnt(16): 8 loads + 16 stores per iter.
__global__ __launch_bounds__(256, 2) void k_attn(const unsigned short* __restrict__ Qb,
                                                 const unsigned short* __restrict__ Kb,
                                                 const unsigned short* __restrict__ VTb,
                                                 float* __restrict__ attn,
                                                 unsigned short* __restrict__ ctx) {
    __shared__ unsigned short Ks[128 * 64];
    __shared__ unsigned short Vs[64 * 128];
    __shared__ unsigned short Ps[4][32][136];

    const int t = threadIdx.x;
    const int w = t >> 6, l = t & 63;

    // XCD-aware bijective remap (dispatch round-robins linear%8 across XCDs)
    const int lin = blockIdx.x + 16 * blockIdx.y;
    const int xcd = lin & 7, idx = lin >> 3;
    const int bh = xcd * 4 + (idx >> 4);
    const int q0 = (idx & 15) * 128;
    const int b = bh >> 4, h = bh & 15;
    const float scale = 0.125f;  // 1/sqrt(64)

    bf16x8 qf[2][2];
#pragma unroll
    for (int mi = 0; mi < 2; ++mi)
#pragma unroll
        for (int kk = 0; kk < 2; ++kk)
            qf[mi][kk] = *reinterpret_cast<const bf16x8*>(
                Qb + (size_t)(b * Sn + q0 + w * 32 + mi * 16 + (l & 15)) * Dn + h * DEP +
                kk * 32 + (l >> 4) * 8);

    const int krow = t >> 3;
    const int kcolswz = ((t & 7) * 8) ^ ((krow & 7) << 3);
    const int vrow = t >> 4;
    const int vcolswz = ((t & 15) * 8) ^ ((vrow & 7) << 3);
    unsigned short* lK = Ks + t * 8;
    unsigned short* lV = Vs + t * 8;

    f32x4 ctxa[2][4] = {};
    float* const abase = attn + (size_t)bh * Sn * Sn + (size_t)(q0 + w * 32) * Sn;

    auto STAGE = [&](int kb) {
#pragma unroll
        for (int is = 0; is < 4; ++is) {
            gll16(Kb + (size_t)(b * Sn + kb * 128 + is * 32 + krow) * Dn + h * DEP + kcolswz,
                  lK + is * 2048);
            gll16(VTb + (size_t)(bh * DEP + is * 16 + vrow) * Sn + kb * 128 + vcolswz,
                  lV + is * 2048);
        }
    };

    // QK^T -> relu/scale -> P (bf16) into per-wave Ps
    auto QKT = [&]() {
        f32x4 sa[2][8];
#pragma unroll
        for (int mi = 0; mi < 2; ++mi)
#pragma unroll
            for (int nj = 0; nj < 8; ++nj)
                sa[mi][nj] = (f32x4){0.f, 0.f, 0.f, 0.f};
#pragma unroll
        for (int nj = 0; nj < 8; ++nj) {
            const int kr = nj * 16 + (l & 15);
#pragma unroll
            for (int kk = 0; kk < 2; ++kk) {
                const int kidx = (kr * 64 + kk * 32 + (l >> 4) * 8) ^ ((kr & 7) << 3);
                const bf16x8 bfr = *reinterpret_cast<const bf16x8*>(Ks + kidx);
                sa[0][nj] = __builtin_amdgcn_mfma_f32_16x16x32_bf16(qf[0][kk], bfr, sa[0][nj], 0, 0, 0);
                sa[1][nj] = __builtin_amdgcn_mfma_f32_16x16x32_bf16(qf[1][kk], bfr, sa[1][nj], 0, 0, 0);
            }
        }
#pragma unroll
        for (int mi = 0; mi < 2; ++mi) {
#pragma unroll
            for (int nj = 0; nj < 8; ++nj) {
                const int kc = nj * 16 + (l & 15);
#pragma unroll
                for (int i = 0; i < 4; ++i) {
                    float p = sa[mi][nj][i] * scale;
                    p = p > 0.f ? p : 0.f;
                    Ps[w][mi * 16 + (l >> 4) * 4 + i][kc] = f2bf(p);
                }
            }
        }
    };

    auto PV = [&]() {
        bf16x8 pf[2][4];
#pragma unroll
        for (int mi = 0; mi < 2; ++mi)
#pragma unroll
            for (int kk = 0; kk < 4; ++kk)
                pf[mi][kk] = *reinterpret_cast<const bf16x8*>(
                    &Ps[w][mi * 16 + (l & 15)][kk * 32 + (l >> 4) * 8]);
#pragma unroll
        for (int nd = 0; nd < 4; ++nd) {
            const int vr = nd * 16 + (l & 15);
#pragma unroll
            for (int kk = 0; kk < 4; ++kk) {
                const int vidx = (vr * 128 + kk * 32 + (l >> 4) * 8) ^ ((vr & 7) << 3);
                const bf16x8 vfr = *reinterpret_cast<const bf16x8*>(Vs + vidx);
                ctxa[0][nd] = __builtin_amdgcn_mfma_f32_16x16x32_bf16(pf[0][kk], vfr, ctxa[0][nd], 0, 0, 0);
                ctxa[1][nd] = __builtin_amdgcn_mfma_f32_16x16x32_bf16(pf[1][kk], vfr, ctxa[1][nd], 0, 0, 0);
            }
        }
    };

    // Full-line NON-TEMPORAL attn stores from Ps: per j, 8 rows x (8 lanes x
    // 16B) = aligned 128B lines; no-allocate keeps K/V resident in L2.
    auto STORE_PS = [&](int kb) {
        float* arow = abase + kb * 128;
#pragma unroll
        for (int j = 0; j < 16; ++j) {
            const int row = (j & 3) * 8 + (l >> 3);
            const int col = (l & 7) * 4 + (j >> 2) * 32;
            ushort4 p = *reinterpret_cast<const ushort4*>(&Ps[w][row][col]);
            f32x4 v;
            v[0] = __uint_as_float((unsigned)p.x << 16);
            v[1] = __uint_as_float((unsigned)p.y << 16);
            v[2] = __uint_as_float((unsigned)p.z << 16);
            v[3] = __uint_as_float((unsigned)p.w << 16);
            __builtin_nontemporal_store(v, reinterpret_cast<f32x4*>(arow + (size_t)row * Sn + col));
        }
    };

    STAGE(0);
    asm volatile("s_waitcnt vmcnt(0)" ::: "memory");
    __builtin_amdgcn_s_barrier();
    __builtin_amdgcn_sched_barrier(0);
    QKT();
    PV();

    for (int kb = 1; kb < Sn / 128; ++kb) {
        asm volatile("s_waitcnt lgkmcnt(0)" ::: "memory");
        __builtin_amdgcn_s_barrier();
        __builtin_amdgcn_sched_barrier(0);
        STAGE(kb);                             // 8 loads (oldest)
        asm volatile("" ::: "memory");         // keep stores after loads in issue order
        STORE_PS(kb - 1);                      // 16 full-line nt stores from Ps
        asm volatile("s_waitcnt vmcnt(16)" ::: "memory");  // loads retired, stores free
        __builtin_amdgcn_s_barrier();
        __builtin_amdgcn_sched_barrier(0);
        QKT();
        PV();
    }
    STORE_PS(Sn / 128 - 1);

#pragma unroll
    for (int mi = 0; mi < 2; ++mi) {
#pragma unroll
        for (int nd = 0; nd < 4; ++nd) {
            const int dc = nd * 16 + (l & 15);
#pragma unroll
            for (int i = 0; i < 4; ++i) {
                const int qr = q0 + w * 32 + mi * 16 + (l >> 4) * 4 + i;
                ctx[(size_t)(b * Sn + qr) * Dn + h * DEP + dc] = f2bf(ctxa[mi][nd][i]);
            }
        }
    }
}

extern "C" void kernel_launch(void* const* d_in, const int* in_sizes, int n_in,
                              void* d_out, int out_size, void* d_ws, size_t ws_size,
                              hipStream_t stream) {
    (void)in_sizes; (void)n_in; (void)out_size; (void)ws_size;
    const float* x  = (const float*)d_in[0];
    const float* wq = (const float*)d_in[1];
    const float* bq = (const float*)d_in[2];
    const float* wk = (const float*)d_in[3];
    const float* bk = (const float*)d_in[4];
    const float* wv = (const float*)d_in[5];
    const float* bv = (const float*)d_in[6];
    const float* wo = (const float*)d_in[7];
    const float* bo = (const float*)d_in[8];

    float* out  = (float*)d_out;
    float* attn = out + (size_t)Bn * Sn * Dn;  // outputs concatenated: (out, attn)

    char* ws = (char*)d_ws;
    unsigned short* xb = (unsigned short*)ws;  ws += (size_t)NTOKn * Dn * 2;       // 8 MB
    unsigned short* wT = (unsigned short*)ws;  ws += (size_t)4 * Dn * Dn * 2;      // 8 MB [q,k,v,o]
    unsigned short* qkv = (unsigned short*)ws; ws += (size_t)3 * NTOKn * Dn * 2;   // 24 MB (v third unused)
    unsigned short* vT = (unsigned short*)ws;  ws += (size_t)NTOKn * Dn * 2;       // 8 MB
    unsigned short* ctx = (unsigned short*)ws;                                     // 8 MB

    const size_t DD = (size_t)Dn * Dn;

    static bool attr_set = false;
    if (!attr_set) {
        hipFuncSetAttribute(reinterpret_cast<const void*>(k_qkv8),
                            hipFuncAttributeMaxDynamicSharedMemorySize, 131072);
        attr_set = true;
    }

    k_prep<<<dim3(5120), 256, 0, stream>>>(x, wq, wk, wv, wo, xb,
                                           wT, wT + DD, wT + 2 * DD, wT + 3 * DD);
    k_qkv8<<<dim3(16, 12), 512, 131072, stream>>>(xb, wT, bq, bk, bv, qkv, vT);
    k_attn<<<dim3(16, 32), 256, 0, stream>>>(qkv, qkv + (size_t)NTOKn * Dn, vT, attn, ctx);
    k_gemm_op<<<dim3(32, 8), 256, 0, stream>>>(ctx, wT + 3 * DD, bo, out, NTOKn, Dn, Dn);
}

// Round 16
// 197.930 us; speedup vs baseline: 1.3424x; 1.0015x over previous
//
#include <hip/hip_runtime.h>
#include <hip/hip_bf16.h>

// Problem constants (reference: B=2, S=2048, D=1024, H=16, DEPTH=64)
constexpr int Bn = 2, Sn = 2048, Dn = 1024, Hn = 16, DEP = 64;
constexpr int NTOKn = Bn * Sn;  // 4096 rows for the token-dim GEMMs

typedef __bf16 bf16x8 __attribute__((ext_vector_type(8)));
typedef float f32x4 __attribute__((ext_vector_type(4)));

__device__ __forceinline__ unsigned short f2bf(float f) {
    union { __hip_bfloat16 h; unsigned short u; } cv;
    cv.h = __float2bfloat16(f);
    return cv.u;
}

// async global->LDS, 16B per lane. LDS dest must be wave-uniform base + lane*16.
__device__ __forceinline__ void gll16(const void* g, void* l) {
    __builtin_amdgcn_global_load_lds(
        (const __attribute__((address_space(1))) unsigned int*)g,
        (__attribute__((address_space(3))) unsigned int*)l, 16, 0, 0);
}

// ---------------- fused prep: x f32->bf16 convert + 4x weight transpose ----------------
__global__ __launch_bounds__(256) void k_prep(const float* __restrict__ x,
                                              const float* __restrict__ w0,
                                              const float* __restrict__ w1,
                                              const float* __restrict__ w2,
                                              const float* __restrict__ w3,
                                              unsigned short* __restrict__ xb,
                                              unsigned short* __restrict__ t0,
                                              unsigned short* __restrict__ t1,
                                              unsigned short* __restrict__ t2,
                                              unsigned short* __restrict__ t3) {
    const int bid = blockIdx.x;
    const int t = threadIdx.x;
    if (bid < 4096) {
        const int idx = (bid * 256 + t) * 4;
        float4 v = *reinterpret_cast<const float4*>(x + idx);
        ushort4 o;
        o.x = f2bf(v.x); o.y = f2bf(v.y); o.z = f2bf(v.z); o.w = f2bf(v.w);
        *reinterpret_cast<ushort4*>(xb + idx) = o;
        return;
    }
    const int b2 = bid - 4096;
    const float* w; unsigned short* tp;
    switch (b2 >> 8) {
        case 0: w = w0; tp = t0; break;
        case 1: w = w1; tp = t1; break;
        case 2: w = w2; tp = t2; break;
        default: w = w3; tp = t3; break;
    }
    __shared__ unsigned short tile[64][65];
    const int k0 = ((b2 & 255) >> 4) * 64, n0 = (b2 & 15) * 64;
    const int c = t & 63, rb = t >> 6;
#pragma unroll
    for (int i = 0; i < 16; ++i) {
        int r = rb + i * 4;
        tile[r][c] = f2bf(w[(size_t)(k0 + r) * Dn + n0 + c]);
    }
    __syncthreads();
#pragma unroll
    for (int i = 0; i < 16; ++i) {
        int n = rb + i * 4;
        tp[(size_t)(n0 + n) * Dn + k0 + c] = tile[c][n];
    }
}

// =================== QKV GEMM, 8-phase-style 256x256 tile ===================
// (counted vmcnt(4), T2 slot-swizzle, T5 setprio)
// Epilogue: Q/K blocks write qkv[z][token][dim]; V blocks (z==2) write the
// TRANSPOSED vT[(b*1024+col)][s] directly as ushort4.
__global__ __launch_bounds__(512, 2) void k_qkv8(const unsigned short* __restrict__ A,
                                                 const unsigned short* __restrict__ Bt,
                                                 const float* __restrict__ bq,
                                                 const float* __restrict__ bk,
                                                 const float* __restrict__ bv,
                                                 unsigned short* __restrict__ qkv,
                                                 unsigned short* __restrict__ vT) {
    extern __shared__ char smem[];  // 131072 bytes
    constexpr int K = 1024, NT = K / 64;  // 16 K-steps

    const int t = threadIdx.x;
    const int w = t >> 6, l = t & 63;
    const int wm = w >> 2, wn = w & 3;
    const int m0 = blockIdx.x * 256;
    const int n0 = blockIdx.y * 256;
    const int z = n0 >> 10;

    const float* bias = (z == 0) ? bq : (z == 1 ? bk : bv);
    float biasv[4];
#pragma unroll
    for (int nf = 0; nf < 4; ++nf)
        biasv[nf] = bias[(n0 + wn * 64 + nf * 16 + (l & 15)) & 1023];

    int aoff[2], boff[2], ldsoff[2];
#pragma unroll
    for (int i = 0; i < 2; ++i) {
        const int idx = i * 512 + t;
        const int row = idx >> 2;
        const int s = ((idx & 3) - row - (row >> 2)) & 3;
        aoff[i] = (m0 + row) * K + s * 8;
        boff[i] = (n0 + row) * K + s * 8;
        ldsoff[i] = idx * 16;
    }

    f32x4 acc[8][4] = {};

#pragma unroll
    for (int kh = 0; kh < 2; ++kh) {
        if (kh == 0) {
#pragma unroll
            for (int i = 0; i < 2; ++i) gll16(A + aoff[i], smem + ldsoff[i]);
#pragma unroll
            for (int i = 0; i < 2; ++i) gll16(Bt + boff[i], smem + 65536 + ldsoff[i]);
        } else {
#pragma unroll
            for (int i = 0; i < 2; ++i) gll16(A + aoff[i] + 32, smem + 16384 + ldsoff[i]);
#pragma unroll
            for (int i = 0; i < 2; ++i) gll16(Bt + boff[i] + 32, smem + 65536 + 16384 + ldsoff[i]);
        }
    }

    for (int kb = 0; kb < NT; ++kb) {
        const int c = kb & 1;
        const int kn = (kb + 1 < NT) ? kb + 1 : NT - 1;
        const int cn = c ^ 1;
        const int Abase = c * 32768;
        const int Bbase = 65536 + c * 32768;
        const int AbaseN = cn * 32768;
        const int BbaseN = 65536 + cn * 32768;

        bf16x8 bf[4], af[4];

#pragma unroll
        for (int ph = 0; ph < 4; ++ph) {
            const int kk = ph >> 1;
            const int mb = (ph & 1) * 4;

            if ((ph & 1) == 0) {
                asm volatile("s_waitcnt vmcnt(4)" ::: "memory");
            }
            __builtin_amdgcn_s_barrier();
            __builtin_amdgcn_sched_barrier(0);

            if ((ph & 1) == 0) {
#pragma unroll
                for (int nf = 0; nf < 4; ++nf) {
                    const int row = wn * 64 + nf * 16 + (l & 15);
                    const int byte = Bbase + kk * 16384 + row * 64 +
                                     ((((l >> 4) + row + (row >> 2)) & 3) * 16);
                    bf[nf] = *reinterpret_cast<const bf16x8*>(smem + byte);
                }
            }
#pragma unroll
            for (int mfl = 0; mfl < 4; ++mfl) {
                const int row = wm * 128 + (mb + mfl) * 16 + (l & 15);
                const int byte = Abase + kk * 16384 + row * 64 +
                                 ((((l >> 4) + row + (row >> 2)) & 3) * 16);
                af[mfl] = *reinterpret_cast<const bf16x8*>(smem + byte);
            }

            {
                const int khs = ph >> 1;
                if ((ph & 1) == 0) {
#pragma unroll
                    for (int i = 0; i < 2; ++i)
                        gll16(A + aoff[i] + kn * 64 + khs * 32,
                              smem + AbaseN + khs * 16384 + ldsoff[i]);
                } else {
#pragma unroll
                    for (int i = 0; i < 2; ++i)
                        gll16(Bt + boff[i] + kn * 64 + khs * 32,
                              smem + BbaseN + khs * 16384 + ldsoff[i]);
                }
            }

            asm volatile("s_waitcnt lgkmcnt(0)" ::: "memory");
            __builtin_amdgcn_sched_barrier(0);
            __builtin_amdgcn_s_setprio(1);
#pragma unroll
            for (int mfl = 0; mfl < 4; ++mfl)
#pragma unroll
                for (int nf = 0; nf < 4; ++nf)
                    acc[mb + mfl][nf] = __builtin_amdgcn_mfma_f32_16x16x32_bf16(
                        af[mfl], bf[nf], acc[mb + mfl][nf], 0, 0, 0);
            __builtin_amdgcn_s_setprio(0);
        }
    }

    asm volatile("s_waitcnt vmcnt(0)" ::: "memory");

    if (z < 2) {
        unsigned short* outz = qkv + (size_t)z * NTOKn * Dn;
#pragma unroll
        for (int mf = 0; mf < 8; ++mf) {
            const int row = m0 + wm * 128 + mf * 16 + (l >> 4) * 4;
#pragma unroll
            for (int nf = 0; nf < 4; ++nf) {
                const int col = (n0 + wn * 64 + nf * 16 + (l & 15)) & 1023;
#pragma unroll
                for (int i = 0; i < 4; ++i)
                    outz[(size_t)(row + i) * Dn + col] = f2bf(acc[mf][nf][i] + biasv[nf]);
            }
        }
    } else {
        // V: write transposed vT[(b*1024 + col)][s], 4 consecutive s per lane
#pragma unroll
        for (int mf = 0; mf < 8; ++mf) {
            const int row = m0 + wm * 128 + mf * 16 + (l >> 4) * 4;
            const int b = row >> 11, s = row & 2047;
#pragma unroll
            for (int nf = 0; nf < 4; ++nf) {
                const int col = (n0 + wn * 64 + nf * 16 + (l & 15)) & 1023;
                ushort4 o;
                o.x = f2bf(acc[mf][nf][0] + biasv[nf]);
                o.y = f2bf(acc[mf][nf][1] + biasv[nf]);
                o.z = f2bf(acc[mf][nf][2] + biasv[nf]);
                o.w = f2bf(acc[mf][nf][3] + biasv[nf]);
                *reinterpret_cast<ushort4*>(vT + ((size_t)(b * 1024 + col)) * Sn + s) = o;
            }
        }
    }
}

// ---------------- bf16 GEMM (m97 structure, 128x128) for the out-projection ----------------
// Epilogue: LDS-bounced FULL-LINE NON-TEMPORAL stores. out is never re-read on
// device -> nt keeps ctx/wTo panels resident in L2 (the R15-proven mechanism).
// 4 chunks of 32 rows x 128 cols f32; each dwordx4 store covers aligned 128B
// lines (32 consecutive lanes per 512B row-slice). Raw s_barrier + lgkm-only
// waits so nt stores stay in flight.
__global__ __launch_bounds__(256) void k_gemm_op(const unsigned short* __restrict__ A,
                                                 const unsigned short* __restrict__ Bt,
                                                 const float* __restrict__ bias,
                                                 float* __restrict__ C,
                                                 int M, int N, int K) {
    __shared__ unsigned short As[128][32];
    __shared__ unsigned short Bs[128][32];
    __shared__ float obuf[32][132];  // +4 pad: kills 4-way write bank conflict
    const int t = threadIdx.x;
    const int w = t >> 6, l = t & 63;
    const int m0 = blockIdx.x * 128, n0 = blockIdx.y * 128;
    const int wr = (w >> 1) * 64, wc = (w & 1) * 64;

    const int lrow = t >> 2;
    const int lcol = (t & 3) * 8;
    const unsigned short* gA = A + (size_t)(m0 + lrow) * K + lcol;
    const unsigned short* gB = Bt + (size_t)(n0 + lrow) * K + lcol;
    unsigned short* lA = &As[0][0] + t * 8;
    unsigned short* lB = &Bs[0][0] + t * 8;

    f32x4 acc[4][4] = {};

    for (int k0 = 0; k0 < K; k0 += 32) {
        __syncthreads();
        gll16(gA + k0, lA);
        gll16(gA + (size_t)64 * K + k0, lA + 2048);
        gll16(gB + k0, lB);
        gll16(gB + (size_t)64 * K + k0, lB + 2048);
        __syncthreads();

        bf16x8 af[4], bfv[4];
#pragma unroll
        for (int i = 0; i < 4; ++i)
            af[i] = *reinterpret_cast<const bf16x8*>(&As[wr + i * 16 + (l & 15)][(l >> 4) * 8]);
#pragma unroll
        for (int i = 0; i < 4; ++i)
            bfv[i] = *reinterpret_cast<const bf16x8*>(&Bs[wc + i * 16 + (l & 15)][(l >> 4) * 8]);
#pragma unroll
        for (int mi = 0; mi < 4; ++mi)
#pragma unroll
            for (int ni = 0; ni < 4; ++ni)
                acc[mi][ni] =
                    __builtin_amdgcn_mfma_f32_16x16x32_bf16(af[mi], bfv[ni], acc[mi][ni], 0, 0, 0);
    }

    // ---- epilogue: 4 chunks of 32 rows, full-line nt stores ----
#pragma unroll
    for (int c = 0; c < 4; ++c) {
        asm volatile("s_waitcnt lgkmcnt(0)" ::: "memory");
        __builtin_amdgcn_s_barrier();                 // prev chunk's obuf reads done
        if ((wr != 0) == (c >= 2)) {                  // my wr-half owns this chunk
            const int mi0 = (c & 1) * 2;
#pragma unroll
            for (int mm = 0; mm < 2; ++mm) {
                const int mi = mi0 + mm;
                const int lr = mi * 16 + (l >> 4) * 4 - (c & 1) * 32;  // 0..31
#pragma unroll
                for (int ni = 0; ni < 4; ++ni) {
                    const int col = wc + ni * 16 + (l & 15);
                    const float bv = bias[n0 + col];
#pragma unroll
                    for (int i = 0; i < 4; ++i)
                        obuf[lr + i][col] = acc[mi][ni][i] + bv;
                }
            }
        }
        asm volatile("s_waitcnt lgkmcnt(0)" ::: "memory");
        __builtin_amdgcn_s_barrier();                 // chunk written
#pragma unroll
        for (int j = 0; j < 4; ++j) {
            const int row = j * 8 + (t >> 5);
            const int c4 = (t & 31) * 4;
            f32x4 v = *reinterpret_cast<const f32x4*>(&obuf[row][c4]);
            __builtin_nontemporal_store(
                v, reinterpret_cast<f32x4*>(C + (size_t)(m0 + c * 32 + row) * N + n0 + c4));
        }
    }
}

// ---------------- fused attention: attn = relu(QK^T*scale), ctx = attn @ V ----------------
// R15 structure: full-line NON-TEMPORAL attn stores sourced from bf16 Ps tile;
// counted vmcnt(16); XCD-aware remap; 2 blocks/CU.
__global__ __launch_bounds__(256, 2) void k_attn(const unsigned short* __restrict__ Qb,
                                                 const unsigned short* __restrict__ Kb,
                                                 const unsigned short* __restrict__ VTb,
                                                 float* __restrict__ attn,
                                                 unsigned short* __restrict__ ctx) {
    __shared__ unsigned short Ks[128 * 64];
    __shared__ unsigned short Vs[64 * 128];
    __shared__ unsigned short Ps[4][32][136];

    const int t = threadIdx.x;
    const int w = t >> 6, l = t & 63;

    // XCD-aware bijective remap (dispatch round-robins linear%8 across XCDs)
    const int lin = blockIdx.x + 16 * blockIdx.y;
    const int xcd = lin & 7, idx = lin >> 3;
    const int bh = xcd * 4 + (idx >> 4);
    const int q0 = (idx & 15) * 128;
    const int b = bh >> 4, h = bh & 15;
    const float scale = 0.125f;  // 1/sqrt(64)

    bf16x8 qf[2][2];
#pragma unroll
    for (int mi = 0; mi < 2; ++mi)
#pragma unroll
        for (int kk = 0; kk < 2; ++kk)
            qf[mi][kk] = *reinterpret_cast<const bf16x8*>(
                Qb + (size_t)(b * Sn + q0 + w * 32 + mi * 16 + (l & 15)) * Dn + h * DEP +
                kk * 32 + (l >> 4) * 8);

    const int krow = t >> 3;
    const int kcolswz = ((t & 7) * 8) ^ ((krow & 7) << 3);
    const int vrow = t >> 4;
    const int vcolswz = ((t & 15) * 8) ^ ((vrow & 7) << 3);
    unsigned short* lK = Ks + t * 8;
    unsigned short* lV = Vs + t * 8;

    f32x4 ctxa[2][4] = {};
    float* const abase = attn + (size_t)bh * Sn * Sn + (size_t)(q0 + w * 32) * Sn;

    auto STAGE = [&](int kb) {
#pragma unroll
        for (int is = 0; is < 4; ++is) {
            gll16(Kb + (size_t)(b * Sn + kb * 128 + is * 32 + krow) * Dn + h * DEP + kcolswz,
                  lK + is * 2048);
            gll16(VTb + (size_t)(bh * DEP + is * 16 + vrow) * Sn + kb * 128 + vcolswz,
                  lV + is * 2048);
        }
    };

    // QK^T -> relu/scale -> P (bf16) into per-wave Ps
    auto QKT = [&]() {
        f32x4 sa[2][8];
#pragma unroll
        for (int mi = 0; mi < 2; ++mi)
#pragma unroll
            for (int nj = 0; nj < 8; ++nj)
                sa[mi][nj] = (f32x4){0.f, 0.f, 0.f, 0.f};
#pragma unroll
        for (int nj = 0; nj < 8; ++nj) {
            const int kr = nj * 16 + (l & 15);
#pragma unroll
            for (int kk = 0; kk < 2; ++kk) {
                const int kidx = (kr * 64 + kk * 32 + (l >> 4) * 8) ^ ((kr & 7) << 3);
                const bf16x8 bfr = *reinterpret_cast<const bf16x8*>(Ks + kidx);
                sa[0][nj] = __builtin_amdgcn_mfma_f32_16x16x32_bf16(qf[0][kk], bfr, sa[0][nj], 0, 0, 0);
                sa[1][nj] = __builtin_amdgcn_mfma_f32_16x16x32_bf16(qf[1][kk], bfr, sa[1][nj], 0, 0, 0);
            }
        }
#pragma unroll
        for (int mi = 0; mi < 2; ++mi) {
#pragma unroll
            for (int nj = 0; nj < 8; ++nj) {
                const int kc = nj * 16 + (l & 15);
#pragma unroll
                for (int i = 0; i < 4; ++i) {
                    float p = sa[mi][nj][i] * scale;
                    p = p > 0.f ? p : 0.f;
                    Ps[w][mi * 16 + (l >> 4) * 4 + i][kc] = f2bf(p);
                }
            }
        }
    };

    auto PV = [&]() {
        bf16x8 pf[2][4];
#pragma unroll
        for (int mi = 0; mi < 2; ++mi)
#pragma unroll
            for (int kk = 0; kk < 4; ++kk)
                pf[mi][kk] = *reinterpret_cast<const bf16x8*>(
                    &Ps[w][mi * 16 + (l & 15)][kk * 32 + (l >> 4) * 8]);
#pragma unroll
        for (int nd = 0; nd < 4; ++nd) {
            const int vr = nd * 16 + (l & 15);
#pragma unroll
            for (int kk = 0; kk < 4; ++kk) {
                const int vidx = (vr * 128 + kk * 32 + (l >> 4) * 8) ^ ((vr & 7) << 3);
                const bf16x8 vfr = *reinterpret_cast<const bf16x8*>(Vs + vidx);
                ctxa[0][nd] = __builtin_amdgcn_mfma_f32_16x16x32_bf16(pf[0][kk], vfr, ctxa[0][nd], 0, 0, 0);
                ctxa[1][nd] = __builtin_amdgcn_mfma_f32_16x16x32_bf16(pf[1][kk], vfr, ctxa[1][nd], 0, 0, 0);
            }
        }
    };

    // Full-line NON-TEMPORAL attn stores from Ps: per j, 8 rows x (8 lanes x
    // 16B) = aligned 128B lines; no-allocate keeps K/V resident in L2.
    auto STORE_PS = [&](int kb) {
        float* arow = abase + kb * 128;
#pragma unroll
        for (int j = 0; j < 16; ++j) {
            const int row = (j & 3) * 8 + (l >> 3);
            const int col = (l & 7) * 4 + (j >> 2) * 32;
            ushort4 p = *reinterpret_cast<const ushort4*>(&Ps[w][row][col]);
            f32x4 v;
            v[0] = __uint_as_float((unsigned)p.x << 16);
            v[1] = __uint_as_float((unsigned)p.y << 16);
            v[2] = __uint_as_float((unsigned)p.z << 16);
            v[3] = __uint_as_float((unsigned)p.w << 16);
            __builtin_nontemporal_store(v, reinterpret_cast<f32x4*>(arow + (size_t)row * Sn + col));
        }
    };

    STAGE(0);
    asm volatile("s_waitcnt vmcnt(0)" ::: "memory");
    __builtin_amdgcn_s_barrier();
    __builtin_amdgcn_sched_barrier(0);
    QKT();
    PV();

    for (int kb = 1; kb < Sn / 128; ++kb) {
        asm volatile("s_waitcnt lgkmcnt(0)" ::: "memory");
        __builtin_amdgcn_s_barrier();
        __builtin_amdgcn_sched_barrier(0);
        STAGE(kb);                             // 8 loads (oldest)
        asm volatile("" ::: "memory");         // keep stores after loads in issue order
        STORE_PS(kb - 1);                      // 16 full-line nt stores from Ps
        asm volatile("s_waitcnt vmcnt(16)" ::: "memory");  // loads retired, stores free
        __builtin_amdgcn_s_barrier();
        __builtin_amdgcn_sched_barrier(0);
        QKT();
        PV();
    }
    STORE_PS(Sn / 128 - 1);

#pragma unroll
    for (int mi = 0; mi < 2; ++mi) {
#pragma unroll
        for (int nd = 0; nd < 4; ++nd) {
            const int dc = nd * 16 + (l & 15);
#pragma unroll
            for (int i = 0; i < 4; ++i) {
                const int qr = q0 + w * 32 + mi * 16 + (l >> 4) * 4 + i;
                ctx[(size_t)(b * Sn + qr) * Dn + h * DEP + dc] = f2bf(ctxa[mi][nd][i]);
            }
        }
    }
}

extern "C" void kernel_launch(void* const* d_in, const int* in_sizes, int n_in,
                              void* d_out, int out_size, void* d_ws, size_t ws_size,
                              hipStream_t stream) {
    (void)in_sizes; (void)n_in; (void)out_size; (void)ws_size;
    const float* x  = (const float*)d_in[0];
    const float* wq = (const float*)d_in[1];
    const float* bq = (const float*)d_in[2];
    const float* wk = (const float*)d_in[3];
    const float* bk = (const float*)d_in[4];
    const float* wv = (const float*)d_in[5];
    const float* bv = (const float*)d_in[6];
    const float* wo = (const float*)d_in[7];
    const float* bo = (const float*)d_in[8];

    float* out  = (float*)d_out;
    float* attn = out + (size_t)Bn * Sn * Dn;  // outputs concatenated: (out, attn)

    char* ws = (char*)d_ws;
    unsigned short* xb = (unsigned short*)ws;  ws += (size_t)NTOKn * Dn * 2;       // 8 MB
    unsigned short* wT = (unsigned short*)ws;  ws += (size_t)4 * Dn * Dn * 2;      // 8 MB [q,k,v,o]
    unsigned short* qkv = (unsigned short*)ws; ws += (size_t)3 * NTOKn * Dn * 2;   // 24 MB (v third unused)
    unsigned short* vT = (unsigned short*)ws;  ws += (size_t)NTOKn * Dn * 2;       // 8 MB
    unsigned short* ctx = (unsigned short*)ws;                                     // 8 MB

    const size_t DD = (size_t)Dn * Dn;

    static bool attr_set = false;
    if (!attr_set) {
        hipFuncSetAttribute(reinterpret_cast<const void*>(k_qkv8),
                            hipFuncAttributeMaxDynamicSharedMemorySize, 131072);
        attr_set = true;
    }

    k_prep<<<dim3(5120), 256, 0, stream>>>(x, wq, wk, wv, wo, xb,
                                           wT, wT + DD, wT + 2 * DD, wT + 3 * DD);
    k_qkv8<<<dim3(16, 12), 512, 131072, stream>>>(xb, wT, bq, bk, bv, qkv, vT);
    k_attn<<<dim3(16, 32), 256, 0, stream>>>(qkv, qkv + (size_t)NTOKn * Dn, vT, attn, ctx);
    k_gemm_op<<<dim3(32, 8), 256, 0, stream>>>(ctx, wT + 3 * DD, bo, out, NTOKn, Dn, Dn);
}

// Round 18
// 195.242 us; speedup vs baseline: 1.3609x; 1.0138x over previous
//
#include <hip/hip_runtime.h>
#include <hip/hip_bf16.h>

// Problem constants (reference: B=2, S=2048, D=1024, H=16, DEPTH=64)
constexpr int Bn = 2, Sn = 2048, Dn = 1024, Hn = 16, DEP = 64;
constexpr int NTOKn = Bn * Sn;  // 4096 rows for the token-dim GEMMs

typedef __bf16 bf16x8 __attribute__((ext_vector_type(8)));
typedef float f32x4 __attribute__((ext_vector_type(4)));

__device__ __forceinline__ unsigned short f2bf(float f) {
    union { __hip_bfloat16 h; unsigned short u; } cv;
    cv.h = __float2bfloat16(f);
    return cv.u;
}

// async global->LDS, 16B per lane. LDS dest must be wave-uniform base + lane*16.
__device__ __forceinline__ void gll16(const void* g, void* l) {
    __builtin_amdgcn_global_load_lds(
        (const __attribute__((address_space(1))) unsigned int*)g,
        (__attribute__((address_space(3))) unsigned int*)l, 16, 0, 0);
}

// ---------------- fused prep: x f32->bf16 convert + 4x weight transpose ----------------
__global__ __launch_bounds__(256) void k_prep(const float* __restrict__ x,
                                              const float* __restrict__ w0,
                                              const float* __restrict__ w1,
                                              const float* __restrict__ w2,
                                              const float* __restrict__ w3,
                                              unsigned short* __restrict__ xb,
                                              unsigned short* __restrict__ t0,
                                              unsigned short* __restrict__ t1,
                                              unsigned short* __restrict__ t2,
                                              unsigned short* __restrict__ t3) {
    const int bid = blockIdx.x;
    const int t = threadIdx.x;
    if (bid < 4096) {
        const int idx = (bid * 256 + t) * 4;
        float4 v = *reinterpret_cast<const float4*>(x + idx);
        ushort4 o;
        o.x = f2bf(v.x); o.y = f2bf(v.y); o.z = f2bf(v.z); o.w = f2bf(v.w);
        *reinterpret_cast<ushort4*>(xb + idx) = o;
        return;
    }
    const int b2 = bid - 4096;
    const float* w; unsigned short* tp;
    switch (b2 >> 8) {
        case 0: w = w0; tp = t0; break;
        case 1: w = w1; tp = t1; break;
        case 2: w = w2; tp = t2; break;
        default: w = w3; tp = t3; break;
    }
    __shared__ unsigned short tile[64][65];
    const int k0 = ((b2 & 255) >> 4) * 64, n0 = (b2 & 15) * 64;
    const int c = t & 63, rb = t >> 6;
#pragma unroll
    for (int i = 0; i < 16; ++i) {
        int r = rb + i * 4;
        tile[r][c] = f2bf(w[(size_t)(k0 + r) * Dn + n0 + c]);
    }
    __syncthreads();
#pragma unroll
    for (int i = 0; i < 16; ++i) {
        int n = rb + i * 4;
        tp[(size_t)(n0 + n) * Dn + k0 + c] = tile[c][n];
    }
}

// =================== QKV GEMM, 8-phase-style 256x256 tile ===================
// (counted vmcnt(4), T2 slot-swizzle, T5 setprio)
// Epilogue: Q/K blocks write qkv[z][token][dim]; V blocks (z==2) write the
// TRANSPOSED vT[(b*1024+col)][s] directly as ushort4.
__global__ __launch_bounds__(512, 2) void k_qkv8(const unsigned short* __restrict__ A,
                                                 const unsigned short* __restrict__ Bt,
                                                 const float* __restrict__ bq,
                                                 const float* __restrict__ bk,
                                                 const float* __restrict__ bv,
                                                 unsigned short* __restrict__ qkv,
                                                 unsigned short* __restrict__ vT) {
    extern __shared__ char smem[];  // 131072 bytes
    constexpr int K = 1024, NT = K / 64;  // 16 K-steps

    const int t = threadIdx.x;
    const int w = t >> 6, l = t & 63;
    const int wm = w >> 2, wn = w & 3;
    const int m0 = blockIdx.x * 256;
    const int n0 = blockIdx.y * 256;
    const int z = n0 >> 10;

    const float* bias = (z == 0) ? bq : (z == 1 ? bk : bv);
    float biasv[4];
#pragma unroll
    for (int nf = 0; nf < 4; ++nf)
        biasv[nf] = bias[(n0 + wn * 64 + nf * 16 + (l & 15)) & 1023];

    int aoff[2], boff[2], ldsoff[2];
#pragma unroll
    for (int i = 0; i < 2; ++i) {
        const int idx = i * 512 + t;
        const int row = idx >> 2;
        const int s = ((idx & 3) - row - (row >> 2)) & 3;
        aoff[i] = (m0 + row) * K + s * 8;
        boff[i] = (n0 + row) * K + s * 8;
        ldsoff[i] = idx * 16;
    }

    f32x4 acc[8][4] = {};

#pragma unroll
    for (int kh = 0; kh < 2; ++kh) {
        if (kh == 0) {
#pragma unroll
            for (int i = 0; i < 2; ++i) gll16(A + aoff[i], smem + ldsoff[i]);
#pragma unroll
            for (int i = 0; i < 2; ++i) gll16(Bt + boff[i], smem + 65536 + ldsoff[i]);
        } else {
#pragma unroll
            for (int i = 0; i < 2; ++i) gll16(A + aoff[i] + 32, smem + 16384 + ldsoff[i]);
#pragma unroll
            for (int i = 0; i < 2; ++i) gll16(Bt + boff[i] + 32, smem + 65536 + 16384 + ldsoff[i]);
        }
    }

    for (int kb = 0; kb < NT; ++kb) {
        const int c = kb & 1;
        const int kn = (kb + 1 < NT) ? kb + 1 : NT - 1;
        const int cn = c ^ 1;
        const int Abase = c * 32768;
        const int Bbase = 65536 + c * 32768;
        const int AbaseN = cn * 32768;
        const int BbaseN = 65536 + cn * 32768;

        bf16x8 bf[4], af[4];

#pragma unroll
        for (int ph = 0; ph < 4; ++ph) {
            const int kk = ph >> 1;
            const int mb = (ph & 1) * 4;

            if ((ph & 1) == 0) {
                asm volatile("s_waitcnt vmcnt(4)" ::: "memory");
            }
            __builtin_amdgcn_s_barrier();
            __builtin_amdgcn_sched_barrier(0);

            if ((ph & 1) == 0) {
#pragma unroll
                for (int nf = 0; nf < 4; ++nf) {
                    const int row = wn * 64 + nf * 16 + (l & 15);
                    const int byte = Bbase + kk * 16384 + row * 64 +
                                     ((((l >> 4) + row + (row >> 2)) & 3) * 16);
                    bf[nf] = *reinterpret_cast<const bf16x8*>(smem + byte);
                }
            }
#pragma unroll
            for (int mfl = 0; mfl < 4; ++mfl) {
                const int row = wm * 128 + (mb + mfl) * 16 + (l & 15);
                const int byte = Abase + kk * 16384 + row * 64 +
                                 ((((l >> 4) + row + (row >> 2)) & 3) * 16);
                af[mfl] = *reinterpret_cast<const bf16x8*>(smem + byte);
            }

            {
                const int khs = ph >> 1;
                if ((ph & 1) == 0) {
#pragma unroll
                    for (int i = 0; i < 2; ++i)
                        gll16(A + aoff[i] + kn * 64 + khs * 32,
                              smem + AbaseN + khs * 16384 + ldsoff[i]);
                } else {
#pragma unroll
                    for (int i = 0; i < 2; ++i)
                        gll16(Bt + boff[i] + kn * 64 + khs * 32,
                              smem + BbaseN + khs * 16384 + ldsoff[i]);
                }
            }

            asm volatile("s_waitcnt lgkmcnt(0)" ::: "memory");
            __builtin_amdgcn_sched_barrier(0);
            __builtin_amdgcn_s_setprio(1);
#pragma unroll
            for (int mfl = 0; mfl < 4; ++mfl)
#pragma unroll
                for (int nf = 0; nf < 4; ++nf)
                    acc[mb + mfl][nf] = __builtin_amdgcn_mfma_f32_16x16x32_bf16(
                        af[mfl], bf[nf], acc[mb + mfl][nf], 0, 0, 0);
            __builtin_amdgcn_s_setprio(0);
        }
    }

    asm volatile("s_waitcnt vmcnt(0)" ::: "memory");

    if (z < 2) {
        unsigned short* outz = qkv + (size_t)z * NTOKn * Dn;
#pragma unroll
        for (int mf = 0; mf < 8; ++mf) {
            const int row = m0 + wm * 128 + mf * 16 + (l >> 4) * 4;
#pragma unroll
            for (int nf = 0; nf < 4; ++nf) {
                const int col = (n0 + wn * 64 + nf * 16 + (l & 15)) & 1023;
#pragma unroll
                for (int i = 0; i < 4; ++i)
                    outz[(size_t)(row + i) * Dn + col] = f2bf(acc[mf][nf][i] + biasv[nf]);
            }
        }
    } else {
        // V: write transposed vT[(b*1024 + col)][s], 4 consecutive s per lane
#pragma unroll
        for (int mf = 0; mf < 8; ++mf) {
            const int row = m0 + wm * 128 + mf * 16 + (l >> 4) * 4;
            const int b = row >> 11, s = row & 2047;
#pragma unroll
            for (int nf = 0; nf < 4; ++nf) {
                const int col = (n0 + wn * 64 + nf * 16 + (l & 15)) & 1023;
                ushort4 o;
                o.x = f2bf(acc[mf][nf][0] + biasv[nf]);
                o.y = f2bf(acc[mf][nf][1] + biasv[nf]);
                o.z = f2bf(acc[mf][nf][2] + biasv[nf]);
                o.w = f2bf(acc[mf][nf][3] + biasv[nf]);
                *reinterpret_cast<ushort4*>(vT + ((size_t)(b * 1024 + col)) * Sn + s) = o;
            }
        }
    }
}

// ---------------- bf16 GEMM (m97 structure, 128x128) for the out-projection ----------------
// Epilogue: LDS-bounced full-line non-temporal stores (R16).
__global__ __launch_bounds__(256) void k_gemm_op(const unsigned short* __restrict__ A,
                                                 const unsigned short* __restrict__ Bt,
                                                 const float* __restrict__ bias,
                                                 float* __restrict__ C,
                                                 int M, int N, int K) {
    __shared__ unsigned short As[128][32];
    __shared__ unsigned short Bs[128][32];
    __shared__ float obuf[32][132];  // +4 pad: kills 4-way write bank conflict
    const int t = threadIdx.x;
    const int w = t >> 6, l = t & 63;
    const int m0 = blockIdx.x * 128, n0 = blockIdx.y * 128;
    const int wr = (w >> 1) * 64, wc = (w & 1) * 64;

    const int lrow = t >> 2;
    const int lcol = (t & 3) * 8;
    const unsigned short* gA = A + (size_t)(m0 + lrow) * K + lcol;
    const unsigned short* gB = Bt + (size_t)(n0 + lrow) * K + lcol;
    unsigned short* lA = &As[0][0] + t * 8;
    unsigned short* lB = &Bs[0][0] + t * 8;

    f32x4 acc[4][4] = {};

    for (int k0 = 0; k0 < K; k0 += 32) {
        __syncthreads();
        gll16(gA + k0, lA);
        gll16(gA + (size_t)64 * K + k0, lA + 2048);
        gll16(gB + k0, lB);
        gll16(gB + (size_t)64 * K + k0, lB + 2048);
        __syncthreads();

        bf16x8 af[4], bfv[4];
#pragma unroll
        for (int i = 0; i < 4; ++i)
            af[i] = *reinterpret_cast<const bf16x8*>(&As[wr + i * 16 + (l & 15)][(l >> 4) * 8]);
#pragma unroll
        for (int i = 0; i < 4; ++i)
            bfv[i] = *reinterpret_cast<const bf16x8*>(&Bs[wc + i * 16 + (l & 15)][(l >> 4) * 8]);
#pragma unroll
        for (int mi = 0; mi < 4; ++mi)
#pragma unroll
            for (int ni = 0; ni < 4; ++ni)
                acc[mi][ni] =
                    __builtin_amdgcn_mfma_f32_16x16x32_bf16(af[mi], bfv[ni], acc[mi][ni], 0, 0, 0);
    }

    // ---- epilogue: 4 chunks of 32 rows, full-line nt stores ----
#pragma unroll
    for (int c = 0; c < 4; ++c) {
        asm volatile("s_waitcnt lgkmcnt(0)" ::: "memory");
        __builtin_amdgcn_s_barrier();                 // prev chunk's obuf reads done
        if ((wr != 0) == (c >= 2)) {                  // my wr-half owns this chunk
            const int mi0 = (c & 1) * 2;
#pragma unroll
            for (int mm = 0; mm < 2; ++mm) {
                const int mi = mi0 + mm;
                const int lr = mi * 16 + (l >> 4) * 4 - (c & 1) * 32;  // 0..31
#pragma unroll
                for (int ni = 0; ni < 4; ++ni) {
                    const int col = wc + ni * 16 + (l & 15);
                    const float bv = bias[n0 + col];
#pragma unroll
                    for (int i = 0; i < 4; ++i)
                        obuf[lr + i][col] = acc[mi][ni][i] + bv;
                }
            }
        }
        asm volatile("s_waitcnt lgkmcnt(0)" ::: "memory");
        __builtin_amdgcn_s_barrier();                 // chunk written
#pragma unroll
        for (int j = 0; j < 4; ++j) {
            const int row = j * 8 + (t >> 5);
            const int c4 = (t & 31) * 4;
            f32x4 v = *reinterpret_cast<const f32x4*>(&obuf[row][c4]);
            __builtin_nontemporal_store(
                v, reinterpret_cast<f32x4*>(C + (size_t)(m0 + c * 32 + row) * N + n0 + c4));
        }
    }
}

// ---------------- fused attention: attn = relu(QK^T*scale), ctx = attn @ V ----------------
// R15 structure + SWAPPED QK^T (R9-verified mapping): sa = mfma(K_frag, Q_frag)
// puts q-row in l&15 and 4 consecutive k-cols in (l>>4)*4+i, so the P->LDS
// scatter is 16x ds_write_b64 instead of 64x ds_write_b16 (-48 LDS instrs per
// wave-iter; attn is LDS-issue-heavy). sa dies inside QKT (no R9 quad-liveness
// hazard). STORE_PS (nt full-line from Ps), PV, vmcnt(16): unchanged from R15.
__global__ __launch_bounds__(256, 2) void k_attn(const unsigned short* __restrict__ Qb,
                                                 const unsigned short* __restrict__ Kb,
                                                 const unsigned short* __restrict__ VTb,
                                                 float* __restrict__ attn,
                                                 unsigned short* __restrict__ ctx) {
    __shared__ unsigned short Ks[128 * 64];
    __shared__ unsigned short Vs[64 * 128];
    __shared__ unsigned short Ps[4][32][136];

    const int t = threadIdx.x;
    const int w = t >> 6, l = t & 63;

    // XCD-aware bijective remap (dispatch round-robins linear%8 across XCDs)
    const int lin = blockIdx.x + 16 * blockIdx.y;
    const int xcd = lin & 7, idx = lin >> 3;
    const int bh = xcd * 4 + (idx >> 4);
    const int q0 = (idx & 15) * 128;
    const int b = bh >> 4, h = bh & 15;
    const float scale = 0.125f;  // 1/sqrt(64)

    bf16x8 qf[2][2];
#pragma unroll
    for (int mi = 0; mi < 2; ++mi)
#pragma unroll
        for (int kk = 0; kk < 2; ++kk)
            qf[mi][kk] = *reinterpret_cast<const bf16x8*>(
                Qb + (size_t)(b * Sn + q0 + w * 32 + mi * 16 + (l & 15)) * Dn + h * DEP +
                kk * 32 + (l >> 4) * 8);

    const int krow = t >> 3;
    const int kcolswz = ((t & 7) * 8) ^ ((krow & 7) << 3);
    const int vrow = t >> 4;
    const int vcolswz = ((t & 15) * 8) ^ ((vrow & 7) << 3);
    unsigned short* lK = Ks + t * 8;
    unsigned short* lV = Vs + t * 8;

    f32x4 ctxa[2][4] = {};
    float* const abase = attn + (size_t)bh * Sn * Sn + (size_t)(q0 + w * 32) * Sn;

    auto STAGE = [&](int kb) {
#pragma unroll
        for (int is = 0; is < 4; ++is) {
            gll16(Kb + (size_t)(b * Sn + kb * 128 + is * 32 + krow) * Dn + h * DEP + kcolswz,
                  lK + is * 2048);
            gll16(VTb + (size_t)(bh * DEP + is * 16 + vrow) * Sn + kb * 128 + vcolswz,
                  lV + is * 2048);
        }
    };

    // Swapped QK^T -> relu/scale -> P (bf16) into per-wave Ps via ushort4 writes
    auto QKT = [&]() {
        f32x4 sa[2][8];
#pragma unroll
        for (int mi = 0; mi < 2; ++mi)
#pragma unroll
            for (int nj = 0; nj < 8; ++nj)
                sa[mi][nj] = (f32x4){0.f, 0.f, 0.f, 0.f};
#pragma unroll
        for (int nj = 0; nj < 8; ++nj) {
            const int kr = nj * 16 + (l & 15);
#pragma unroll
            for (int kk = 0; kk < 2; ++kk) {
                const int kidx = (kr * 64 + kk * 32 + (l >> 4) * 8) ^ ((kr & 7) << 3);
                const bf16x8 kfr = *reinterpret_cast<const bf16x8*>(Ks + kidx);
                // swapped: K as A-operand, Q as B-operand (R9-verified)
                sa[0][nj] = __builtin_amdgcn_mfma_f32_16x16x32_bf16(kfr, qf[0][kk], sa[0][nj], 0, 0, 0);
                sa[1][nj] = __builtin_amdgcn_mfma_f32_16x16x32_bf16(kfr, qf[1][kk], sa[1][nj], 0, 0, 0);
            }
        }
#pragma unroll
        for (int mi = 0; mi < 2; ++mi) {
            const int prow = mi * 16 + (l & 15);
            const int pcol = (l >> 4) * 4;
#pragma unroll
            for (int nj = 0; nj < 8; ++nj) {
                f32x4 v = sa[mi][nj];
#pragma unroll
                for (int i = 0; i < 4; ++i) {
                    float p = v[i] * scale;
                    v[i] = p > 0.f ? p : 0.f;
                }
                ushort4 pk;
                pk.x = f2bf(v[0]); pk.y = f2bf(v[1]); pk.z = f2bf(v[2]); pk.w = f2bf(v[3]);
                *reinterpret_cast<ushort4*>(&Ps[w][prow][nj * 16 + pcol]) = pk;
            }
        }
    };

    auto PV = [&]() {
        bf16x8 pf[2][4];
#pragma unroll
        for (int mi = 0; mi < 2; ++mi)
#pragma unroll
            for (int kk = 0; kk < 4; ++kk)
                pf[mi][kk] = *reinterpret_cast<const bf16x8*>(
                    &Ps[w][mi * 16 + (l & 15)][kk * 32 + (l >> 4) * 8]);
#pragma unroll
        for (int nd = 0; nd < 4; ++nd) {
            const int vr = nd * 16 + (l & 15);
#pragma unroll
            for (int kk = 0; kk < 4; ++kk) {
                const int vidx = (vr * 128 + kk * 32 + (l >> 4) * 8) ^ ((vr & 7) << 3);
                const bf16x8 vfr = *reinterpret_cast<const bf16x8*>(Vs + vidx);
                ctxa[0][nd] = __builtin_amdgcn_mfma_f32_16x16x32_bf16(pf[0][kk], vfr, ctxa[0][nd], 0, 0, 0);
                ctxa[1][nd] = __builtin_amdgcn_mfma_f32_16x16x32_bf16(pf[1][kk], vfr, ctxa[1][nd], 0, 0, 0);
            }
        }
    };

    // Full-line NON-TEMPORAL attn stores from Ps (R15): per j, 8 rows x
    // (8 lanes x 16B) = aligned 128B lines.
    auto STORE_PS = [&](int kb) {
        float* arow = abase + kb * 128;
#pragma unroll
        for (int j = 0; j < 16; ++j) {
            const int row = (j & 3) * 8 + (l >> 3);
            const int col = (l & 7) * 4 + (j >> 2) * 32;
            ushort4 p = *reinterpret_cast<const ushort4*>(&Ps[w][row][col]);
            f32x4 v;
            v[0] = __uint_as_float((unsigned)p.x << 16);
            v[1] = __uint_as_float((unsigned)p.y << 16);
            v[2] = __uint_as_float((unsigned)p.z << 16);
            v[3] = __uint_as_float((unsigned)p.w << 16);
            __builtin_nontemporal_store(v, reinterpret_cast<f32x4*>(arow + (size_t)row * Sn + col));
        }
    };

    STAGE(0);
    asm volatile("s_waitcnt vmcnt(0)" ::: "memory");
    __builtin_amdgcn_s_barrier();
    __builtin_amdgcn_sched_barrier(0);
    QKT();
    PV();

    for (int kb = 1; kb < Sn / 128; ++kb) {
        asm volatile("s_waitcnt lgkmcnt(0)" ::: "memory");
        __builtin_amdgcn_s_barrier();
        __builtin_amdgcn_sched_barrier(0);
        STAGE(kb);                             // 8 loads (oldest)
        asm volatile("" ::: "memory");         // keep stores after loads in issue order
        STORE_PS(kb - 1);                      // 16 full-line nt stores from Ps
        asm volatile("s_waitcnt vmcnt(16)" ::: "memory");  // loads retired, stores free
        __builtin_amdgcn_s_barrier();
        __builtin_amdgcn_sched_barrier(0);
        QKT();
        PV();
    }
    STORE_PS(Sn / 128 - 1);

#pragma unroll
    for (int mi = 0; mi < 2; ++mi) {
#pragma unroll
        for (int nd = 0; nd < 4; ++nd) {
            const int dc = nd * 16 + (l & 15);
#pragma unroll
            for (int i = 0; i < 4; ++i) {
                const int qr = q0 + w * 32 + mi * 16 + (l >> 4) * 4 + i;
                ctx[(size_t)(b * Sn + qr) * Dn + h * DEP + dc] = f2bf(ctxa[mi][nd][i]);
            }
        }
    }
}

extern "C" void kernel_launch(void* const* d_in, const int* in_sizes, int n_in,
                              void* d_out, int out_size, void* d_ws, size_t ws_size,
                              hipStream_t stream) {
    (void)in_sizes; (void)n_in; (void)out_size; (void)ws_size;
    const float* x  = (const float*)d_in[0];
    const float* wq = (const float*)d_in[1];
    const float* bq = (const float*)d_in[2];
    const float* wk = (const float*)d_in[3];
    const float* bk = (const float*)d_in[4];
    const float* wv = (const float*)d_in[5];
    const float* bv = (const float*)d_in[6];
    const float* wo = (const float*)d_in[7];
    const float* bo = (const float*)d_in[8];

    float* out  = (float*)d_out;
    float* attn = out + (size_t)Bn * Sn * Dn;  // outputs concatenated: (out, attn)

    char* ws = (char*)d_ws;
    unsigned short* xb = (unsigned short*)ws;  ws += (size_t)NTOKn * Dn * 2;       // 8 MB
    unsigned short* wT = (unsigned short*)ws;  ws += (size_t)4 * Dn * Dn * 2;      // 8 MB [q,k,v,o]
    unsigned short* qkv = (unsigned short*)ws; ws += (size_t)3 * NTOKn * Dn * 2;   // 24 MB (v third unused)
    unsigned short* vT = (unsigned short*)ws;  ws += (size_t)NTOKn * Dn * 2;       // 8 MB
    unsigned short* ctx = (unsigned short*)ws;                                     // 8 MB

    const size_t DD = (size_t)Dn * Dn;

    static bool attr_set = false;
    if (!attr_set) {
        hipFuncSetAttribute(reinterpret_cast<const void*>(k_qkv8),
                            hipFuncAttributeMaxDynamicSharedMemorySize, 131072);
        attr_set = true;
    }

    k_prep<<<dim3(5120), 256, 0, stream>>>(x, wq, wk, wv, wo, xb,
                                           wT, wT + DD, wT + 2 * DD, wT + 3 * DD);
    k_qkv8<<<dim3(16, 12), 512, 131072, stream>>>(xb, wT, bq, bk, bv, qkv, vT);
    k_attn<<<dim3(16, 32), 256, 0, stream>>>(qkv, qkv + (size_t)NTOKn * Dn, vT, attn, ctx);
    k_gemm_op<<<dim3(32, 8), 256, 0, stream>>>(ctx, wT + 3 * DD, bo, out, NTOKn, Dn, Dn);
}